// Round 2
// baseline (3139.590 us; speedup 1.0000x reference)
//
#include <hip/hip_runtime.h>
#include <hip/hip_bf16.h>
#include <math.h>

#define NTHREADS 256

// ---------------- CSR-by-dst construction ----------------

__global__ void zero_int_kernel(int* __restrict__ p, int n) {
    int i = blockIdx.x * blockDim.x + threadIdx.x;
    if (i < n) p[i] = 0;
}

__global__ void hist_kernel(const int* __restrict__ dst, int* __restrict__ counts, int E) {
    int e = blockIdx.x * blockDim.x + threadIdx.x;
    if (e < E) atomicAdd(&counts[dst[e]], 1);
}

// single block, 256 threads; Nn must be divisible by 256
__global__ void scan_kernel(const int* __restrict__ counts, int* __restrict__ row_ofs, int Nn) {
    __shared__ int partial[NTHREADS];
    int tid = threadIdx.x;
    int chunk = Nn / NTHREADS;
    int base = tid * chunk;
    int sum = 0;
    for (int i = 0; i < chunk; ++i) sum += counts[base + i];
    partial[tid] = sum;
    __syncthreads();
    if (tid == 0) {
        int acc = 0;
        for (int i = 0; i < NTHREADS; ++i) { int v = partial[i]; partial[i] = acc; acc += v; }
        row_ofs[Nn] = acc;
    }
    __syncthreads();
    int acc = partial[tid];
    for (int i = 0; i < chunk; ++i) { row_ofs[base + i] = acc; acc += counts[base + i]; }
}

__global__ void scatter_kernel(const int* __restrict__ dst, const int* __restrict__ row_ofs,
                               int* __restrict__ cursor, int* __restrict__ perm, int E) {
    int e = blockIdx.x * blockDim.x + threadIdx.x;
    if (e < E) {
        int d = dst[e];
        int pos = atomicAdd(&cursor[d], 1);
        perm[row_ofs[d] + pos] = e;
    }
}

// ---------------- w_as/w_ad precompute: wv[h*DIN+i] = sum_c W[i, h*C+c] * a[h,c] ----------------
__global__ void wvec_kernel(const float* __restrict__ W,   // [DIN, H*C]
                            const float* __restrict__ a_s, // [H, C]
                            const float* __restrict__ a_d, // [H, C]
                            float* __restrict__ w_as,      // [H, DIN]
                            float* __restrict__ w_ad,
                            int DIN, int H, int C) {
    int gid = blockIdx.x * blockDim.x + threadIdx.x;
    int wid = gid >> 6;
    int lane = threadIdx.x & 63;
    if (wid >= H * DIN) return;
    int h = wid / DIN, i = wid % DIN;
    const float* wp = W + (size_t)i * H * C + (size_t)h * C;
    const float* sp = a_s + (size_t)h * C;
    const float* dp = a_d + (size_t)h * C;
    float ss = 0.f, sd = 0.f;
    for (int c = lane; c < C; c += 64) {
        float v = wp[c];
        ss += v * sp[c];
        sd += v * dp[c];
    }
    #pragma unroll
    for (int off = 32; off > 0; off >>= 1) {
        ss += __shfl_down(ss, off, 64);
        sd += __shfl_down(sd, off, 64);
    }
    if (lane == 0) { w_as[wid] = ss; w_ad[wid] = sd; }
}

// ---------------- alpha dots from a dense feature matrix ----------------
// as_out[n*H+h] = dot(feat[n,:], w_as[h,:]) ; feat is [Nn, D], w is [H, D]
__global__ void alpha_dot_kernel(const float* __restrict__ feat,
                                 const float* __restrict__ w_as,
                                 const float* __restrict__ w_ad,
                                 float* __restrict__ as_out,
                                 float* __restrict__ ad_out,
                                 int Nn, int H, int D) {
    int gid = blockIdx.x * blockDim.x + threadIdx.x;
    int wid = gid >> 6;
    int lane = threadIdx.x & 63;
    if (wid >= Nn * H) return;
    int n = wid / H, hh = wid % H;
    const float* fp = feat + (size_t)n * D;
    const float* sp = w_as + (size_t)hh * D;
    const float* dp = w_ad + (size_t)hh * D;
    float ss = 0.f, sd = 0.f;
    for (int c = lane; c < D; c += 64) {
        float v = fp[c];
        ss += v * sp[c];
        sd += v * dp[c];
    }
    #pragma unroll
    for (int off = 32; off > 0; off >>= 1) {
        ss += __shfl_down(ss, off, 64);
        sd += __shfl_down(sd, off, 64);
    }
    if (lane == 0) { as_out[wid] = ss; ad_out[wid] = sd; }
}

// ---------------- per-edge raw scores (leaky relu) ----------------
__global__ void edge_score_kernel(const int* __restrict__ src, const int* __restrict__ dst,
                                  const float* __restrict__ as, const float* __restrict__ ad,
                                  float* __restrict__ e_out, int E, int H) {
    int i = blockIdx.x * blockDim.x + threadIdx.x;
    if (i >= E * H) return;
    int e = i / H, hh = i % H;
    float v = as[src[e] * H + hh] + ad[dst[e] * H + hh];
    e_out[i] = v > 0.f ? v : 0.2f * v;
}

// ---------------- segment softmax (per dst node, per head); alpha written in place ----------------
__global__ void softmax_kernel(const int* __restrict__ row_ofs, const int* __restrict__ perm,
                               float* __restrict__ escore, int Nn, int H) {
    int i = blockIdx.x * blockDim.x + threadIdx.x;
    if (i >= Nn * H) return;
    int n = i / H, hh = i % H;
    int s = row_ofs[n], t = row_ofs[n + 1];
    if (s == t) return;
    float m = -INFINITY;
    for (int j = s; j < t; ++j) m = fmaxf(m, escore[perm[j] * H + hh]);
    float denom = 0.f;
    for (int j = s; j < t; ++j) denom += __expf(escore[perm[j] * H + hh] - m);
    float inv = 1.f / (denom + 1e-16f);
    for (int j = s; j < t; ++j) {
        float* p = &escore[perm[j] * H + hh];
        *p = __expf(*p - m) * inv;
    }
}

// ---------------- weighted aggregation of a dense feature matrix for ONE head ----------------
// z[n, j] = sum_{e in edges(dst=n)} alpha[e*H+hh] * feat[src[e], j]   (j < D)
// optional bias + elu epilogue (used for the final layer where feat=h2, H=1)
__global__ void aggregate_kernel(const float* __restrict__ feat,   // [N, D]
                                 const float* __restrict__ alpha,  // [E, H]
                                 const int* __restrict__ src,
                                 const int* __restrict__ row_ofs, const int* __restrict__ perm,
                                 const float* __restrict__ bias,   // [D] or null
                                 float* __restrict__ z,            // [N, D]
                                 int H, int hh, int D) {
    int n = blockIdx.x;
    int s = row_ofs[n], t = row_ofs[n + 1];
    for (int j = threadIdx.x; j < D; j += blockDim.x) {
        float acc = 0.f;
        for (int k = s; k < t; ++k) {
            int e = perm[k];
            acc += alpha[(size_t)e * H + hh] * feat[(size_t)src[e] * D + j];
        }
        if (bias) acc += bias[j];
        z[(size_t)n * D + j] = acc;
    }
}

// ---------------- fp32 tiled GEMM: C[M,N] = A[M,K] @ B[K,N] (+accum, +bias, +elu) ----------------
#define BM 64
#define BN 64
#define BK 16
#define LDA (BM + 4)
#define LDB (BN + 4)

__global__ __launch_bounds__(256) void sgemm_kernel(const float* __restrict__ A,
                                                    const float* __restrict__ B,
                                                    float* __restrict__ C,
                                                    int M, int N, int K,
                                                    int ldb,                       // row stride of B
                                                    const float* __restrict__ bias,// [N] or null
                                                    int accum, int elu) {
    __shared__ float As[BK][LDA];
    __shared__ float Bs[BK][LDB];
    int tid = threadIdx.x;
    int bx = blockIdx.x;
    int by = blockIdx.y;
    int row0 = by * BM, col0 = bx * BN;
    int tx = tid & 15, ty = tid >> 4;
    float acc[4][4] = {};

    for (int k0 = 0; k0 < K; k0 += BK) {
        #pragma unroll
        for (int i = 0; i < 4; ++i) {
            int l = tid + i * 256;
            int r = l >> 4, c = l & 15;
            As[c][r] = A[(size_t)(row0 + r) * K + (k0 + c)];
        }
        #pragma unroll
        for (int i = 0; i < 4; ++i) {
            int l = tid + i * 256;
            int r = l >> 6, c = l & 63;
            Bs[r][c] = B[(size_t)(k0 + r) * ldb + (col0 + c)];
        }
        __syncthreads();
        #pragma unroll
        for (int k = 0; k < BK; ++k) {
            float a[4], b[4];
            #pragma unroll
            for (int i = 0; i < 4; ++i) a[i] = As[k][ty * 4 + i];
            #pragma unroll
            for (int j = 0; j < 4; ++j) b[j] = Bs[k][tx * 4 + j];
            #pragma unroll
            for (int i = 0; i < 4; ++i)
                #pragma unroll
                for (int j = 0; j < 4; ++j) acc[i][j] += a[i] * b[j];
        }
        __syncthreads();
    }
    #pragma unroll
    for (int i = 0; i < 4; ++i) {
        #pragma unroll
        for (int j = 0; j < 4; ++j) {
            size_t idx = (size_t)(row0 + ty * 4 + i) * N + (col0 + tx * 4 + j);
            float v = acc[i][j];
            if (accum) v += C[idx];
            if (bias) v += bias[col0 + tx * 4 + j];
            if (elu) v = v > 0.f ? v : expm1f(v);
            C[idx] = v;
        }
    }
}

// ---------------- launch ----------------
extern "C" void kernel_launch(void* const* d_in, const int* in_sizes, int n_in,
                              void* d_out, int out_size, void* d_ws, size_t ws_size,
                              hipStream_t stream) {
    const int N = 8192, E = 65536, DIN = 768, C = 768, H1n = 8;
    const int HC1 = H1n * C;  // 6144

    const float* x    = (const float*)d_in[0];
    const float* W1   = (const float*)d_in[1];
    const float* a_s1 = (const float*)d_in[2];
    const float* a_d1 = (const float*)d_in[3];
    const float* b1   = (const float*)d_in[4];
    const float* W2   = (const float*)d_in[5];
    const float* a_s2 = (const float*)d_in[6];
    const float* a_d2 = (const float*)d_in[7];
    const float* b2   = (const float*)d_in[8];
    const int*   edges = (const int*)d_in[9];
    const int* src = edges;
    const int* dst = edges + E;

    // ---- workspace layout (~80 MB total) ----
    char* w = (char*)d_ws;
    auto alloc = [&](size_t bytes) -> void* {
        void* p = (void*)w;
        w += (bytes + 255) & ~(size_t)255;
        return p;
    };
    float* z       = (float*)alloc((size_t)N * C * 4);     // 25 MB  aggregated x (per head)
    float* o1h     = (float*)alloc((size_t)N * C * 4);     // 25 MB  ELU(z@W1_h + b1_h)
    float* h2      = (float*)alloc((size_t)N * C * 4);     // 25 MB  layer-2 h, accumulated
    float* w_as1   = (float*)alloc((size_t)H1n * DIN * 4);
    float* w_ad1   = (float*)alloc((size_t)H1n * DIN * 4);
    float* as1     = (float*)alloc((size_t)N * H1n * 4);
    float* ad1     = (float*)alloc((size_t)N * H1n * 4);
    float* e1      = (float*)alloc((size_t)E * H1n * 4);   // 2 MB
    float* as2     = (float*)alloc((size_t)N * 4);
    float* ad2     = (float*)alloc((size_t)N * 4);
    float* e2      = (float*)alloc((size_t)E * 4);
    int*   counts  = (int*)alloc((size_t)N * 4);
    int*   cursor  = (int*)alloc((size_t)N * 4);
    int*   row_ofs = (int*)alloc((size_t)(N + 1) * 4);
    int*   perm    = (int*)alloc((size_t)E * 4);

    // ---- CSR by dst ----
    zero_int_kernel<<<(N + 255) / 256, 256, 0, stream>>>(counts, N);
    zero_int_kernel<<<(N + 255) / 256, 256, 0, stream>>>(cursor, N);
    hist_kernel<<<(E + 255) / 256, 256, 0, stream>>>(dst, counts, E);
    scan_kernel<<<1, NTHREADS, 0, stream>>>(counts, row_ofs, N);
    scatter_kernel<<<(E + 255) / 256, 256, 0, stream>>>(dst, row_ofs, cursor, perm, E);

    // ---- Layer 1 attention coefficients (no h1 materialization) ----
    // w_as1[h,i] = sum_c W1[i, h*C+c]*a_s1[h,c]
    {
        int waves = H1n * DIN;  // 6144
        wvec_kernel<<<(waves * 64 + 255) / 256, 256, 0, stream>>>(W1, a_s1, a_d1, w_as1, w_ad1, DIN, H1n, C);
    }
    {
        int waves = N * H1n;  // 65536
        alpha_dot_kernel<<<(waves * 64 + 255) / 256, 256, 0, stream>>>(x, w_as1, w_ad1, as1, ad1, N, H1n, DIN);
    }
    edge_score_kernel<<<(E * H1n + 255) / 256, 256, 0, stream>>>(src, dst, as1, ad1, e1, E, H1n);
    softmax_kernel<<<(N * H1n + 255) / 256, 256, 0, stream>>>(row_ofs, perm, e1, N, H1n);

    // ---- Per-head: aggregate x -> z ; o1h = ELU(z@W1_h + b1_h) ; h2 += o1h@W2_h ----
    for (int h = 0; h < H1n; ++h) {
        aggregate_kernel<<<N, 256, 0, stream>>>(x, e1, src, row_ofs, perm, nullptr, z, H1n, h, DIN);
        {
            dim3 g(C / BN, N / BM);
            // B = W1 columns [h*C, (h+1)*C), row stride HC1
            sgemm_kernel<<<g, 256, 0, stream>>>(z, W1 + (size_t)h * C, o1h,
                                                N, C, DIN, HC1, b1 + (size_t)h * C,
                                                /*accum=*/0, /*elu=*/1);
        }
        {
            dim3 g(C / BN, N / BM);
            // B = W2 rows [h*C, (h+1)*C), full width C
            sgemm_kernel<<<g, 256, 0, stream>>>(o1h, W2 + (size_t)h * C * C, h2,
                                                N, C, C, C, nullptr,
                                                /*accum=*/(h > 0), /*elu=*/0);
        }
    }

    // ---- Layer 2 (H=1) on materialized h2 ----
    {
        int waves = N;  // 8192
        alpha_dot_kernel<<<(waves * 64 + 255) / 256, 256, 0, stream>>>(h2, a_s2, a_d2, as2, ad2, N, 1, C);
    }
    edge_score_kernel<<<(E + 255) / 256, 256, 0, stream>>>(src, dst, as2, ad2, e2, E, 1);
    softmax_kernel<<<(N + 255) / 256, 256, 0, stream>>>(row_ofs, perm, e2, N, 1);
    aggregate_kernel<<<N, 256, 0, stream>>>(h2, e2, src, row_ofs, perm, b2, (float*)d_out, 1, 0, C);
}

// Round 3
// 681.750 us; speedup vs baseline: 4.6052x; 4.6052x over previous
//
#include <hip/hip_runtime.h>
#include <hip/hip_bf16.h>
#include <math.h>

#define NTHREADS 256

typedef __attribute__((ext_vector_type(4))) float f32x4;
typedef __attribute__((ext_vector_type(8))) short s16x8;

// ---------------- CSR-by-dst construction ----------------

__global__ void zero_int_kernel(int* __restrict__ p, int n) {
    int i = blockIdx.x * blockDim.x + threadIdx.x;
    if (i < n) p[i] = 0;
}

__global__ void hist_kernel(const int* __restrict__ dst, int* __restrict__ counts, int E) {
    int e = blockIdx.x * blockDim.x + threadIdx.x;
    if (e < E) atomicAdd(&counts[dst[e]], 1);
}

__global__ void scan_kernel(const int* __restrict__ counts, int* __restrict__ row_ofs, int Nn) {
    __shared__ int partial[NTHREADS];
    int tid = threadIdx.x;
    int chunk = Nn / NTHREADS;
    int base = tid * chunk;
    int sum = 0;
    for (int i = 0; i < chunk; ++i) sum += counts[base + i];
    partial[tid] = sum;
    __syncthreads();
    if (tid == 0) {
        int acc = 0;
        for (int i = 0; i < NTHREADS; ++i) { int v = partial[i]; partial[i] = acc; acc += v; }
        row_ofs[Nn] = acc;
    }
    __syncthreads();
    int acc = partial[tid];
    for (int i = 0; i < chunk; ++i) { row_ofs[base + i] = acc; acc += counts[base + i]; }
}

__global__ void scatter_kernel(const int* __restrict__ dst, const int* __restrict__ row_ofs,
                               int* __restrict__ cursor, int* __restrict__ perm, int E) {
    int e = blockIdx.x * blockDim.x + threadIdx.x;
    if (e < E) {
        int d = dst[e];
        int pos = atomicAdd(&cursor[d], 1);
        perm[row_ofs[d] + pos] = e;
    }
}

// ---------------- w_as/w_ad precompute: wv[h*DIN+i] = sum_c W[i, h*C+c] * a[h,c] ----------------
__global__ void wvec_kernel(const float* __restrict__ W, const float* __restrict__ a_s,
                            const float* __restrict__ a_d, float* __restrict__ w_as,
                            float* __restrict__ w_ad, int DIN, int H, int C) {
    int gid = blockIdx.x * blockDim.x + threadIdx.x;
    int wid = gid >> 6;
    int lane = threadIdx.x & 63;
    if (wid >= H * DIN) return;
    int h = wid / DIN, i = wid % DIN;
    const float* wp = W + (size_t)i * H * C + (size_t)h * C;
    const float* sp = a_s + (size_t)h * C;
    const float* dp = a_d + (size_t)h * C;
    float ss = 0.f, sd = 0.f;
    for (int c = lane; c < C; c += 64) {
        float v = wp[c];
        ss += v * sp[c];
        sd += v * dp[c];
    }
    #pragma unroll
    for (int off = 32; off > 0; off >>= 1) {
        ss += __shfl_down(ss, off, 64);
        sd += __shfl_down(sd, off, 64);
    }
    if (lane == 0) { w_as[wid] = ss; w_ad[wid] = sd; }
}

// ---------------- alpha dots: as_out[n*H+h] = dot(feat[n,:], w_as[h,:]) ----------------
__global__ void alpha_dot_kernel(const float* __restrict__ feat, const float* __restrict__ w_as,
                                 const float* __restrict__ w_ad, float* __restrict__ as_out,
                                 float* __restrict__ ad_out, int Nn, int H, int D) {
    int gid = blockIdx.x * blockDim.x + threadIdx.x;
    int wid = gid >> 6;
    int lane = threadIdx.x & 63;
    if (wid >= Nn * H) return;
    int n = wid / H, hh = wid % H;
    const float* fp = feat + (size_t)n * D;
    const float* sp = w_as + (size_t)hh * D;
    const float* dp = w_ad + (size_t)hh * D;
    float ss = 0.f, sd = 0.f;
    for (int c = lane; c < D; c += 64) {
        float v = fp[c];
        ss += v * sp[c];
        sd += v * dp[c];
    }
    #pragma unroll
    for (int off = 32; off > 0; off >>= 1) {
        ss += __shfl_down(ss, off, 64);
        sd += __shfl_down(sd, off, 64);
    }
    if (lane == 0) { as_out[wid] = ss; ad_out[wid] = sd; }
}

// ---------------- per-edge raw scores (leaky relu) ----------------
__global__ void edge_score_kernel(const int* __restrict__ src, const int* __restrict__ dst,
                                  const float* __restrict__ as, const float* __restrict__ ad,
                                  float* __restrict__ e_out, int E, int H) {
    int i = blockIdx.x * blockDim.x + threadIdx.x;
    if (i >= E * H) return;
    int e = i / H, hh = i % H;
    float v = as[src[e] * H + hh] + ad[dst[e] * H + hh];
    e_out[i] = v > 0.f ? v : 0.2f * v;
}

// ---------------- segment softmax; alpha written in place ----------------
__global__ void softmax_kernel(const int* __restrict__ row_ofs, const int* __restrict__ perm,
                               float* __restrict__ escore, int Nn, int H) {
    int i = blockIdx.x * blockDim.x + threadIdx.x;
    if (i >= Nn * H) return;
    int n = i / H, hh = i % H;
    int s = row_ofs[n], t = row_ofs[n + 1];
    if (s == t) return;
    float m = -INFINITY;
    for (int j = s; j < t; ++j) m = fmaxf(m, escore[perm[j] * H + hh]);
    float denom = 0.f;
    for (int j = s; j < t; ++j) denom += __expf(escore[perm[j] * H + hh] - m);
    float inv = 1.f / (denom + 1e-16f);
    for (int j = s; j < t; ++j) {
        float* p = &escore[perm[j] * H + hh];
        *p = __expf(*p - m) * inv;
    }
}

// ---------------- multi-head aggregation of x -> zG (bf16) ----------------
// zG[n][h*768 + j] = sum_e alpha[e*H + g0+h] * x[src[e]][j]
template <int G>
__global__ void aggregate_heads_kernel(const float4* __restrict__ x4,   // [N][D/4]
                                       const float* __restrict__ alpha, // [E][H]
                                       const int* __restrict__ src,
                                       const int* __restrict__ row_ofs,
                                       const int* __restrict__ perm,
                                       __hip_bfloat16* __restrict__ zG, // [N][G*D]
                                       int H, int g0, int D4) {
    int n = blockIdx.x;
    int s = row_ofs[n], t = row_ofs[n + 1];
    int j = threadIdx.x;  // 0..D4-1 (192 threads)
    float4 acc[G];
    #pragma unroll
    for (int h = 0; h < G; ++h) acc[h] = make_float4(0.f, 0.f, 0.f, 0.f);
    for (int k = s; k < t; ++k) {
        int e = perm[k];
        float4 v = x4[(size_t)src[e] * D4 + j];
        const float* ap = alpha + (size_t)e * H + g0;
        #pragma unroll
        for (int h = 0; h < G; ++h) {
            float a = ap[h];
            acc[h].x += a * v.x; acc[h].y += a * v.y;
            acc[h].z += a * v.z; acc[h].w += a * v.w;
        }
    }
    int D = D4 * 4;
    #pragma unroll
    for (int h = 0; h < G; ++h) {
        size_t o = (size_t)n * G * D + (size_t)h * D + j * 4;
        zG[o + 0] = __float2bfloat16(acc[h].x);
        zG[o + 1] = __float2bfloat16(acc[h].y);
        zG[o + 2] = __float2bfloat16(acc[h].z);
        zG[o + 3] = __float2bfloat16(acc[h].w);
    }
}

// ---------------- final aggregation (fp32, + bias) ----------------
__global__ void aggregate_out_kernel(const float4* __restrict__ feat4, const float* __restrict__ alpha,
                                     const int* __restrict__ src, const int* __restrict__ row_ofs,
                                     const int* __restrict__ perm, const float4* __restrict__ bias4,
                                     float4* __restrict__ out4, int D4) {
    int n = blockIdx.x;
    int s = row_ofs[n], t = row_ofs[n + 1];
    int j = threadIdx.x;
    float4 acc = make_float4(0.f, 0.f, 0.f, 0.f);
    for (int k = s; k < t; ++k) {
        int e = perm[k];
        float a = alpha[e];
        float4 v = feat4[(size_t)src[e] * D4 + j];
        acc.x += a * v.x; acc.y += a * v.y; acc.z += a * v.z; acc.w += a * v.w;
    }
    float4 b = bias4[j];
    acc.x += b.x; acc.y += b.y; acc.z += b.z; acc.w += b.w;
    out4[(size_t)n * D4 + j] = acc;
}

// ---------------- transpose + fp32->bf16: dst[c][r] = bf16(src[r][c]) ----------------
__global__ void transpose_bf16_kernel(const float* __restrict__ src, __hip_bfloat16* __restrict__ dst,
                                      int R, int Cc) {
    __shared__ float tile[32][33];
    int bx = blockIdx.x * 32;  // col base in src
    int by = blockIdx.y * 32;  // row base in src
    int tx = threadIdx.x, ty = threadIdx.y;  // 32 x 8
    #pragma unroll
    for (int i = 0; i < 32; i += 8)
        tile[ty + i][tx] = src[(size_t)(by + ty + i) * Cc + (bx + tx)];
    __syncthreads();
    #pragma unroll
    for (int i = 0; i < 32; i += 8)
        dst[(size_t)(bx + ty + i) * R + (by + tx)] = __float2bfloat16(tile[tx][ty + i]);
}

// ---------------- bf16 MFMA GEMM: C[M,N] = A[M,K] @ BT[N,K]^T ----------------
// 128x128 block tile, BK=32, 256 threads (4 waves, 2x2 of 64x64), global_load_lds staging.
__device__ inline void gload_lds16(const void* g, void* l) {
    __builtin_amdgcn_global_load_lds((const __attribute__((address_space(1))) unsigned int*)g,
                                     (__attribute__((address_space(3))) unsigned int*)l, 16, 0, 0);
}

__global__ __launch_bounds__(256) void gemm_bf16_kernel(
    const __hip_bfloat16* __restrict__ A,   // [M][lda]
    const __hip_bfloat16* __restrict__ BT,  // [N][ldb]
    int lda, int ldb, int ldc,
    int M, int Ncols, int K,
    const float* __restrict__ bias,         // [Ncols] or null
    __hip_bfloat16* __restrict__ Cb,        // bf16 out or null
    float* __restrict__ Cf,                 // fp32 out (used if Cb==null)
    int flags,                              // 1 = elu, 2 = accum (fp32 only)
    long bsA, long bsBT, long bsC, long bsBias) {
    __shared__ short As[128][32];
    __shared__ short Bs[128][32];

    int zb = blockIdx.z;
    A += (size_t)zb * bsA;
    BT += (size_t)zb * bsBT;
    if (Cb) Cb += (size_t)zb * bsC;
    else    Cf += (size_t)zb * bsC;
    if (bias) bias += (size_t)zb * bsBias;

    int tid = threadIdx.x;
    int lane = tid & 63;
    int wv = tid >> 6;
    int wr = (wv >> 1) * 64;  // wave row offset in tile
    int wc = (wv & 1) * 64;   // wave col offset
    int ml = lane & 15;
    int q8 = (lane >> 4) * 8;

    int col0 = blockIdx.x * 128;
    int row0 = blockIdx.y * 128;

    f32x4 acc[4][4];
    #pragma unroll
    for (int i = 0; i < 4; ++i)
        #pragma unroll
        for (int j = 0; j < 4; ++j) acc[i][j] = (f32x4){0.f, 0.f, 0.f, 0.f};

    for (int k0 = 0; k0 < K; k0 += 32) {
        // stage A tile [128][32] and BT tile [128][32]; 512 chunks of 16 B each
        #pragma unroll
        for (int i = 0; i < 2; ++i) {
            int c = tid + i * 256;
            int r = c >> 2;
            int co = (c & 3) << 3;
            gload_lds16(A + (size_t)(row0 + r) * lda + (k0 + co), ((short*)As) + c * 8);
            gload_lds16(BT + (size_t)(col0 + r) * ldb + (k0 + co), ((short*)Bs) + c * 8);
        }
        __syncthreads();
        s16x8 af[4], bfr[4];
        #pragma unroll
        for (int t = 0; t < 4; ++t) af[t] = *(const s16x8*)&As[wr + t * 16 + ml][q8];
        #pragma unroll
        for (int t = 0; t < 4; ++t) bfr[t] = *(const s16x8*)&Bs[wc + t * 16 + ml][q8];
        #pragma unroll
        for (int ti = 0; ti < 4; ++ti)
            #pragma unroll
            for (int tj = 0; tj < 4; ++tj)
                acc[ti][tj] = __builtin_amdgcn_mfma_f32_16x16x32_bf16(af[ti], bfr[tj], acc[ti][tj], 0, 0, 0);
        __syncthreads();
    }

    // epilogue: C/D layout col = lane&15, row = (lane>>4)*4 + r
    int rbase = row0 + wr + (lane >> 4) * 4;
    int cbase = col0 + wc + ml;
    #pragma unroll
    for (int ti = 0; ti < 4; ++ti) {
        #pragma unroll
        for (int tj = 0; tj < 4; ++tj) {
            int col = cbase + tj * 16;
            float bv = bias ? bias[col] : 0.f;
            #pragma unroll
            for (int r = 0; r < 4; ++r) {
                int row = rbase + ti * 16 + r;
                float v = acc[ti][tj][r] + bv;
                if (flags & 1) v = v > 0.f ? v : expm1f(v);
                size_t idx = (size_t)row * ldc + col;
                if (Cb) Cb[idx] = __float2bfloat16(v);
                else {
                    if (flags & 2) v += Cf[idx];
                    Cf[idx] = v;
                }
            }
        }
    }
}

// ---------------- launch ----------------
extern "C" void kernel_launch(void* const* d_in, const int* in_sizes, int n_in,
                              void* d_out, int out_size, void* d_ws, size_t ws_size,
                              hipStream_t stream) {
    const int N = 8192, E = 65536, DIN = 768, C = 768, H1n = 8;

    const float* x    = (const float*)d_in[0];
    const float* W1   = (const float*)d_in[1];
    const float* a_s1 = (const float*)d_in[2];
    const float* a_d1 = (const float*)d_in[3];
    const float* b1   = (const float*)d_in[4];
    const float* W2   = (const float*)d_in[5];
    const float* a_s2 = (const float*)d_in[6];
    const float* a_d2 = (const float*)d_in[7];
    const float* b2   = (const float*)d_in[8];
    const int*   edges = (const int*)d_in[9];
    const int* src = edges;
    const int* dst = edges + E;

    // ---- choose head group size G from ws_size ----
    const size_t fixed_bytes = (size_t)(48) * 1024 * 1024;  // h2 + W1T + W2T + small buffers, padded
    const size_t per_head = (size_t)N * C * 2 * 2;          // zG + o1G per head (bf16)
    int G = 1;
    if (ws_size >= fixed_bytes + 8 * per_head + (1 << 20)) G = 8;
    else if (ws_size >= fixed_bytes + 4 * per_head + (1 << 20)) G = 4;
    else if (ws_size >= fixed_bytes + 2 * per_head + (1 << 20)) G = 2;

    // ---- workspace layout ----
    char* w = (char*)d_ws;
    auto alloc = [&](size_t bytes) -> void* {
        void* p = (void*)w;
        w += (bytes + 255) & ~(size_t)255;
        return p;
    };
    __hip_bfloat16* zG  = (__hip_bfloat16*)alloc((size_t)N * G * C * 2);
    __hip_bfloat16* o1G = (__hip_bfloat16*)alloc((size_t)N * G * C * 2);
    float* h2           = (float*)alloc((size_t)N * C * 4);
    __hip_bfloat16* W1T = (__hip_bfloat16*)alloc((size_t)H1n * C * DIN * 2);  // [6144][768]
    __hip_bfloat16* W2T = (__hip_bfloat16*)alloc((size_t)C * H1n * C * 2);    // [768][6144]
    float* w_as1   = (float*)alloc((size_t)H1n * DIN * 4);
    float* w_ad1   = (float*)alloc((size_t)H1n * DIN * 4);
    float* as1     = (float*)alloc((size_t)N * H1n * 4);
    float* ad1     = (float*)alloc((size_t)N * H1n * 4);
    float* e1      = (float*)alloc((size_t)E * H1n * 4);
    float* as2     = (float*)alloc((size_t)N * 4);
    float* ad2     = (float*)alloc((size_t)N * 4);
    float* e2      = (float*)alloc((size_t)E * 4);
    int*   counts  = (int*)alloc((size_t)N * 4);
    int*   cursor  = (int*)alloc((size_t)N * 4);
    int*   row_ofs = (int*)alloc((size_t)(N + 1) * 4);
    int*   perm    = (int*)alloc((size_t)E * 4);

    // ---- CSR by dst ----
    zero_int_kernel<<<(N + 255) / 256, 256, 0, stream>>>(counts, N);
    zero_int_kernel<<<(N + 255) / 256, 256, 0, stream>>>(cursor, N);
    hist_kernel<<<(E + 255) / 256, 256, 0, stream>>>(dst, counts, E);
    scan_kernel<<<1, NTHREADS, 0, stream>>>(counts, row_ofs, N);
    scatter_kernel<<<(E + 255) / 256, 256, 0, stream>>>(dst, row_ofs, cursor, perm, E);

    // ---- weight transforms (bf16, transposed) ----
    {
        dim3 b(32, 8);
        dim3 g1(H1n * C / 32, DIN / 32);  // W1 [768][6144] -> W1T [6144][768]
        transpose_bf16_kernel<<<g1, b, 0, stream>>>(W1, W1T, DIN, H1n * C);
        dim3 g2(C / 32, H1n * C / 32);    // W2 [6144][768] -> W2T [768][6144]
        transpose_bf16_kernel<<<g2, b, 0, stream>>>(W2, W2T, H1n * C, C);
    }

    // ---- Layer 1 attention coefficients ----
    wvec_kernel<<<(H1n * DIN * 64 + 255) / 256, 256, 0, stream>>>(W1, a_s1, a_d1, w_as1, w_ad1, DIN, H1n, C);
    alpha_dot_kernel<<<((size_t)N * H1n * 64 + 255) / 256, 256, 0, stream>>>(x, w_as1, w_ad1, as1, ad1, N, H1n, DIN);
    edge_score_kernel<<<(E * H1n + 255) / 256, 256, 0, stream>>>(src, dst, as1, ad1, e1, E, H1n);
    softmax_kernel<<<(N * H1n + 255) / 256, 256, 0, stream>>>(row_ofs, perm, e1, N, H1n);

    // ---- head-group loop: aggregate -> GEMM1 (bf16, bias+ELU) -> GEMM2 (accum fp32) ----
    int NG = H1n / G;
    for (int g = 0; g < NG; ++g) {
        int g0 = g * G;
        switch (G) {
            case 8: aggregate_heads_kernel<8><<<N, DIN / 4, 0, stream>>>((const float4*)x, e1, src, row_ofs, perm, zG, H1n, g0, DIN / 4); break;
            case 4: aggregate_heads_kernel<4><<<N, DIN / 4, 0, stream>>>((const float4*)x, e1, src, row_ofs, perm, zG, H1n, g0, DIN / 4); break;
            case 2: aggregate_heads_kernel<2><<<N, DIN / 4, 0, stream>>>((const float4*)x, e1, src, row_ofs, perm, zG, H1n, g0, DIN / 4); break;
            default: aggregate_heads_kernel<1><<<N, DIN / 4, 0, stream>>>((const float4*)x, e1, src, row_ofs, perm, zG, H1n, g0, DIN / 4); break;
        }
        // GEMM1 batched over the G heads: o1G[:, h*C:(h+1)*C] = ELU(z_h @ W1_h + b1_h)
        {
            dim3 grid(C / 128, N / 128, G);
            gemm_bf16_kernel<<<grid, 256, 0, stream>>>(
                zG, W1T + (size_t)g0 * C * DIN, G * C, DIN, G * C,
                N, C, DIN, b1 + (size_t)g0 * C, o1G, nullptr, /*flags=*/1,
                /*bsA=*/C, /*bsBT=*/(long)C * DIN, /*bsC=*/C, /*bsBias=*/C);
        }
        // GEMM2 (one GEMM, K = G*C): h2 (+)= o1G @ W2[g0*C:(g0+G)*C, :]
        {
            dim3 grid(C / 128, N / 128, 1);
            gemm_bf16_kernel<<<grid, 256, 0, stream>>>(
                o1G, W2T + (size_t)g0 * C, G * C, H1n * C, C,
                N, C, G * C, nullptr, nullptr, h2, /*flags=*/(g > 0 ? 2 : 0),
                0, 0, 0, 0);
        }
    }

    // ---- Layer 2 (H=1) on h2 ----
    alpha_dot_kernel<<<((size_t)N * 64 + 255) / 256, 256, 0, stream>>>(h2, a_s2, a_d2, as2, ad2, N, 1, C);
    edge_score_kernel<<<(E + 255) / 256, 256, 0, stream>>>(src, dst, as2, ad2, e2, E, 1);
    softmax_kernel<<<(N + 255) / 256, 256, 0, stream>>>(row_ofs, perm, e2, N, 1);
    aggregate_out_kernel<<<N, C / 4, 0, stream>>>((const float4*)h2, e2, src, row_ofs, perm,
                                                  (const float4*)b2, (float4*)d_out, C / 4);
}

// Round 4
// 636.804 us; speedup vs baseline: 4.9302x; 1.0706x over previous
//
#include <hip/hip_runtime.h>
#include <hip/hip_bf16.h>
#include <math.h>

#define NTHREADS 256

typedef __attribute__((ext_vector_type(4))) float f32x4;
typedef __attribute__((ext_vector_type(8))) short s16x8;

// ---------------- CSR-by-dst construction ----------------

__global__ void zero_int_kernel(int* __restrict__ p, int n) {
    int i = blockIdx.x * blockDim.x + threadIdx.x;
    if (i < n) p[i] = 0;
}

__global__ void hist_kernel(const int* __restrict__ dst, int* __restrict__ counts, int E) {
    int e = blockIdx.x * blockDim.x + threadIdx.x;
    if (e < E) atomicAdd(&counts[dst[e]], 1);
}

__global__ void scan_kernel(const int* __restrict__ counts, int* __restrict__ row_ofs, int Nn) {
    __shared__ int partial[NTHREADS];
    int tid = threadIdx.x;
    int chunk = Nn / NTHREADS;
    int base = tid * chunk;
    int sum = 0;
    for (int i = 0; i < chunk; ++i) sum += counts[base + i];
    partial[tid] = sum;
    __syncthreads();
    if (tid == 0) {
        int acc = 0;
        for (int i = 0; i < NTHREADS; ++i) { int v = partial[i]; partial[i] = acc; acc += v; }
        row_ofs[Nn] = acc;
    }
    __syncthreads();
    int acc = partial[tid];
    for (int i = 0; i < chunk; ++i) { row_ofs[base + i] = acc; acc += counts[base + i]; }
}

__global__ void scatter_kernel(const int* __restrict__ dst, const int* __restrict__ row_ofs,
                               int* __restrict__ cursor, int* __restrict__ perm, int E) {
    int e = blockIdx.x * blockDim.x + threadIdx.x;
    if (e < E) {
        int d = dst[e];
        int pos = atomicAdd(&cursor[d], 1);
        perm[row_ofs[d] + pos] = e;
    }
}

// ---------------- w_as/w_ad precompute: wv[h*DIN+i] = sum_c W[i, h*C+c] * a[h,c] ----------------
__global__ void wvec_kernel(const float* __restrict__ W, const float* __restrict__ a_s,
                            const float* __restrict__ a_d, float* __restrict__ w_as,
                            float* __restrict__ w_ad, int DIN, int H, int C) {
    int gid = blockIdx.x * blockDim.x + threadIdx.x;
    int wid = gid >> 6;
    int lane = threadIdx.x & 63;
    if (wid >= H * DIN) return;
    int h = wid / DIN, i = wid % DIN;
    const float* wp = W + (size_t)i * H * C + (size_t)h * C;
    const float* sp = a_s + (size_t)h * C;
    const float* dp = a_d + (size_t)h * C;
    float ss = 0.f, sd = 0.f;
    for (int c = lane; c < C; c += 64) {
        float v = wp[c];
        ss += v * sp[c];
        sd += v * dp[c];
    }
    #pragma unroll
    for (int off = 32; off > 0; off >>= 1) {
        ss += __shfl_down(ss, off, 64);
        sd += __shfl_down(sd, off, 64);
    }
    if (lane == 0) { w_as[wid] = ss; w_ad[wid] = sd; }
}

// ---------------- layer-1 alpha dots, all 16 w-vectors LDS-cached; one wave per node ----------------
// wv: [16][768] fp32 (rows 0..7 = w_as per head, rows 8..15 = w_ad per head)
__global__ __launch_bounds__(256) void alpha16_kernel(const float4* __restrict__ x4,  // [N][192]
                                                      const float* __restrict__ wv,
                                                      float* __restrict__ as_out,    // [N][8]
                                                      float* __restrict__ ad_out) {
    __shared__ float ws[16 * 768];
    int tid = threadIdx.x;
    #pragma unroll
    for (int i = 0; i < 12; ++i)
        ((float4*)ws)[tid + i * 256] = ((const float4*)wv)[tid + i * 256];
    __syncthreads();
    int wvid = tid >> 6, lane = tid & 63;
    int n = blockIdx.x * 4 + wvid;
    float4 xr[3];
    #pragma unroll
    for (int r = 0; r < 3; ++r) xr[r] = x4[(size_t)n * 192 + lane + 64 * r];
    #pragma unroll
    for (int j = 0; j < 16; ++j) {
        const float4* wj = (const float4*)(ws + j * 768);
        float s = 0.f;
        #pragma unroll
        for (int r = 0; r < 3; ++r) {
            float4 wc = wj[lane + 64 * r];
            s += xr[r].x * wc.x + xr[r].y * wc.y + xr[r].z * wc.z + xr[r].w * wc.w;
        }
        #pragma unroll
        for (int off = 32; off > 0; off >>= 1) s += __shfl_down(s, off, 64);
        if (lane == 0) {
            if (j < 8) as_out[n * 8 + j] = s;
            else       ad_out[n * 8 + (j - 8)] = s;
        }
    }
}

// ---------------- layer-2 alpha dots (H=1) ----------------
__global__ void alpha_dot_kernel(const float* __restrict__ feat, const float* __restrict__ w_as,
                                 const float* __restrict__ w_ad, float* __restrict__ as_out,
                                 float* __restrict__ ad_out, int Nn, int H, int D) {
    int gid = blockIdx.x * blockDim.x + threadIdx.x;
    int wid = gid >> 6;
    int lane = threadIdx.x & 63;
    if (wid >= Nn * H) return;
    int n = wid / H, hh = wid % H;
    const float* fp = feat + (size_t)n * D;
    const float* sp = w_as + (size_t)hh * D;
    const float* dp = w_ad + (size_t)hh * D;
    float ss = 0.f, sd = 0.f;
    for (int c = lane; c < D; c += 64) {
        float v = fp[c];
        ss += v * sp[c];
        sd += v * dp[c];
    }
    #pragma unroll
    for (int off = 32; off > 0; off >>= 1) {
        ss += __shfl_down(ss, off, 64);
        sd += __shfl_down(sd, off, 64);
    }
    if (lane == 0) { as_out[wid] = ss; ad_out[wid] = sd; }
}

// ---------------- per-edge raw scores (leaky relu) ----------------
__global__ void edge_score_kernel(const int* __restrict__ src, const int* __restrict__ dst,
                                  const float* __restrict__ as, const float* __restrict__ ad,
                                  float* __restrict__ e_out, int E, int H) {
    int i = blockIdx.x * blockDim.x + threadIdx.x;
    if (i >= E * H) return;
    int e = i / H, hh = i % H;
    float v = as[src[e] * H + hh] + ad[dst[e] * H + hh];
    e_out[i] = v > 0.f ? v : 0.2f * v;
}

// ---------------- segment softmax; alpha written in place ----------------
__global__ void softmax_kernel(const int* __restrict__ row_ofs, const int* __restrict__ perm,
                               float* __restrict__ escore, int Nn, int H) {
    int i = blockIdx.x * blockDim.x + threadIdx.x;
    if (i >= Nn * H) return;
    int n = i / H, hh = i % H;
    int s = row_ofs[n], t = row_ofs[n + 1];
    if (s == t) return;
    float m = -INFINITY;
    for (int j = s; j < t; ++j) m = fmaxf(m, escore[perm[j] * H + hh]);
    float denom = 0.f;
    for (int j = s; j < t; ++j) denom += __expf(escore[perm[j] * H + hh] - m);
    float inv = 1.f / (denom + 1e-16f);
    for (int j = s; j < t; ++j) {
        float* p = &escore[perm[j] * H + hh];
        *p = __expf(*p - m) * inv;
    }
}

// ---------------- 8-head aggregation of x -> zAB (bf16), single pass ----------------
__global__ void aggregate_heads8_kernel(const float4* __restrict__ x4,   // [N][192]
                                        const float* __restrict__ alpha, // [E][8]
                                        const int* __restrict__ src,
                                        const int* __restrict__ row_ofs,
                                        const int* __restrict__ perm,
                                        __hip_bfloat16* __restrict__ zAB, // [N][8*768]
                                        int D4) {
    int n = blockIdx.x;
    int s = row_ofs[n], t = row_ofs[n + 1];
    int j = threadIdx.x;  // 0..191
    float4 acc[8];
    #pragma unroll
    for (int h = 0; h < 8; ++h) acc[h] = make_float4(0.f, 0.f, 0.f, 0.f);
    for (int k = s; k < t; ++k) {
        int e = perm[k];
        float4 v = x4[(size_t)src[e] * D4 + j];
        const float* ap = alpha + (size_t)e * 8;
        #pragma unroll
        for (int h = 0; h < 8; ++h) {
            float a = ap[h];
            acc[h].x += a * v.x; acc[h].y += a * v.y;
            acc[h].z += a * v.z; acc[h].w += a * v.w;
        }
    }
    int D = D4 * 4;
    #pragma unroll
    for (int h = 0; h < 8; ++h) {
        size_t o = (size_t)n * 8 * D + (size_t)h * D + j * 4;
        zAB[o + 0] = __float2bfloat16(acc[h].x);
        zAB[o + 1] = __float2bfloat16(acc[h].y);
        zAB[o + 2] = __float2bfloat16(acc[h].z);
        zAB[o + 3] = __float2bfloat16(acc[h].w);
    }
}

// ---------------- final aggregation (fp32, + bias) ----------------
__global__ void aggregate_out_kernel(const float4* __restrict__ feat4, const float* __restrict__ alpha,
                                     const int* __restrict__ src, const int* __restrict__ row_ofs,
                                     const int* __restrict__ perm, const float4* __restrict__ bias4,
                                     float4* __restrict__ out4, int D4) {
    int n = blockIdx.x;
    int s = row_ofs[n], t = row_ofs[n + 1];
    int j = threadIdx.x;
    float4 acc = make_float4(0.f, 0.f, 0.f, 0.f);
    for (int k = s; k < t; ++k) {
        int e = perm[k];
        float a = alpha[e];
        float4 v = feat4[(size_t)src[e] * D4 + j];
        acc.x += a * v.x; acc.y += a * v.y; acc.z += a * v.z; acc.w += a * v.w;
    }
    float4 b = bias4[j];
    acc.x += b.x; acc.y += b.y; acc.z += b.z; acc.w += b.w;
    out4[(size_t)n * D4 + j] = acc;
}

// ---------------- transpose + fp32->bf16: dst[c][r] = bf16(src[r][c]) ----------------
__global__ void transpose_bf16_kernel(const float* __restrict__ src, __hip_bfloat16* __restrict__ dst,
                                      int R, int Cc) {
    __shared__ float tile[32][33];
    int bx = blockIdx.x * 32;
    int by = blockIdx.y * 32;
    int tx = threadIdx.x, ty = threadIdx.y;  // 32 x 8
    #pragma unroll
    for (int i = 0; i < 32; i += 8)
        tile[ty + i][tx] = src[(size_t)(by + ty + i) * Cc + (bx + tx)];
    __syncthreads();
    #pragma unroll
    for (int i = 0; i < 32; i += 8)
        dst[(size_t)(bx + ty + i) * R + (by + tx)] = __float2bfloat16(tile[tx][ty + i]);
}

// ---------------- partial reduction: h2 = sum_s partials[s] ----------------
__global__ void reduce_partials_kernel(const float4* __restrict__ parts, float4* __restrict__ h2,
                                       int S, int n4) {
    int i = blockIdx.x * blockDim.x + threadIdx.x;
    if (i >= n4) return;
    float4 a = parts[i];
    for (int s = 1; s < S; ++s) {
        float4 b = parts[(size_t)s * n4 + i];
        a.x += b.x; a.y += b.y; a.z += b.z; a.w += b.w;
    }
    h2[i] = a;
}

// ---------------- bf16 MFMA GEMM: C[M,N] = A[M,K] @ BT[N,K]^T ----------------
// 128x128 tile, BK=32, 256 threads (2x2 waves of 64x64). blockIdx.z = batch (bs*) or K-split (kofs_per_z).
__device__ inline void gload_lds16(const void* g, void* l) {
    __builtin_amdgcn_global_load_lds((const __attribute__((address_space(1))) unsigned int*)g,
                                     (__attribute__((address_space(3))) unsigned int*)l, 16, 0, 0);
}

__global__ __launch_bounds__(256) void gemm_bf16_kernel(
    const __hip_bfloat16* __restrict__ A,   // [M][lda]
    const __hip_bfloat16* __restrict__ BT,  // [N][ldb]
    int lda, int ldb, int ldc,
    int M, int Ncols, int K, int kofs_per_z,
    const float* __restrict__ bias,
    __hip_bfloat16* __restrict__ Cb,        // bf16 out or null
    float* __restrict__ Cf,                 // fp32 out (used if Cb==null)
    int flags,                              // 1 = elu, 2 = accum (fp32 only)
    long bsA, long bsBT, long bsC, long bsBias) {
    __shared__ short As[128][32];
    __shared__ short Bs[128][32];

    int zb = blockIdx.z;
    int kofs = zb * kofs_per_z;
    A += (size_t)zb * bsA;
    BT += (size_t)zb * bsBT;
    if (Cb) Cb += (size_t)zb * bsC;
    else    Cf += (size_t)zb * bsC;
    if (bias) bias += (size_t)zb * bsBias;

    int tid = threadIdx.x;
    int lane = tid & 63;
    int wv = tid >> 6;
    int wr = (wv >> 1) * 64;
    int wc = (wv & 1) * 64;
    int ml = lane & 15;
    int q8 = (lane >> 4) * 8;

    int col0 = blockIdx.x * 128;
    int row0 = blockIdx.y * 128;

    f32x4 acc[4][4];
    #pragma unroll
    for (int i = 0; i < 4; ++i)
        #pragma unroll
        for (int j = 0; j < 4; ++j) acc[i][j] = (f32x4){0.f, 0.f, 0.f, 0.f};

    for (int k0 = 0; k0 < K; k0 += 32) {
        #pragma unroll
        for (int i = 0; i < 2; ++i) {
            int c = tid + i * 256;
            int r = c >> 2;
            int co = (c & 3) << 3;
            gload_lds16(A + (size_t)(row0 + r) * lda + (kofs + k0 + co), ((short*)As) + c * 8);
            gload_lds16(BT + (size_t)(col0 + r) * ldb + (kofs + k0 + co), ((short*)Bs) + c * 8);
        }
        __syncthreads();
        s16x8 af[4], bfr[4];
        #pragma unroll
        for (int t = 0; t < 4; ++t) af[t] = *(const s16x8*)&As[wr + t * 16 + ml][q8];
        #pragma unroll
        for (int t = 0; t < 4; ++t) bfr[t] = *(const s16x8*)&Bs[wc + t * 16 + ml][q8];
        #pragma unroll
        for (int ti = 0; ti < 4; ++ti)
            #pragma unroll
            for (int tj = 0; tj < 4; ++tj)
                acc[ti][tj] = __builtin_amdgcn_mfma_f32_16x16x32_bf16(af[ti], bfr[tj], acc[ti][tj], 0, 0, 0);
        __syncthreads();
    }

    int rbase = row0 + wr + (lane >> 4) * 4;
    int cbase = col0 + wc + ml;
    #pragma unroll
    for (int ti = 0; ti < 4; ++ti) {
        #pragma unroll
        for (int tj = 0; tj < 4; ++tj) {
            int col = cbase + tj * 16;
            float bv = bias ? bias[col] : 0.f;
            #pragma unroll
            for (int r = 0; r < 4; ++r) {
                int row = rbase + ti * 16 + r;
                float v = acc[ti][tj][r] + bv;
                if (flags & 1) v = v > 0.f ? v : expm1f(v);
                size_t idx = (size_t)row * ldc + col;
                if (Cb) Cb[idx] = __float2bfloat16(v);
                else {
                    if (flags & 2) v += Cf[idx];
                    Cf[idx] = v;
                }
            }
        }
    }
}

// ---------------- launch ----------------
extern "C" void kernel_launch(void* const* d_in, const int* in_sizes, int n_in,
                              void* d_out, int out_size, void* d_ws, size_t ws_size,
                              hipStream_t stream) {
    const int N = 8192, E = 65536, DIN = 768, C = 768, H1n = 8;
    const int HC1 = H1n * C;  // 6144

    const float* x    = (const float*)d_in[0];
    const float* W1   = (const float*)d_in[1];
    const float* a_s1 = (const float*)d_in[2];
    const float* a_d1 = (const float*)d_in[3];
    const float* b1   = (const float*)d_in[4];
    const float* W2   = (const float*)d_in[5];
    const float* a_s2 = (const float*)d_in[6];
    const float* a_d2 = (const float*)d_in[7];
    const float* b2   = (const float*)d_in[8];
    const int*   edges = (const int*)d_in[9];
    const int* src = edges;
    const int* dst = edges + E;

    // ---- workspace layout ----
    char* w = (char*)d_ws;
    auto alloc = [&](size_t bytes) -> void* {
        void* p = (void*)w;
        w += (bytes + 255) & ~(size_t)255;
        return p;
    };
    __hip_bfloat16* zAB = (__hip_bfloat16*)alloc((size_t)N * HC1 * 2);      // 100.7 MB (all 8 heads)
    __hip_bfloat16* o1  = (__hip_bfloat16*)alloc((size_t)N * 4 * C * 2);    // 50.3 MB (one 4-head group)
    float* h2           = (float*)alloc((size_t)N * C * 4);                 // 25.2 MB
    __hip_bfloat16* W1T = (__hip_bfloat16*)alloc((size_t)HC1 * DIN * 2);    // 9.4 MB
    __hip_bfloat16* W2T = (__hip_bfloat16*)alloc((size_t)C * HC1 * 2);      // 9.4 MB
    float* wv      = (float*)alloc((size_t)16 * DIN * 4);   // rows 0..7 w_as1, 8..15 w_ad1
    float* as1     = (float*)alloc((size_t)N * H1n * 4);
    float* ad1     = (float*)alloc((size_t)N * H1n * 4);
    float* e1      = (float*)alloc((size_t)E * H1n * 4);
    float* as2     = (float*)alloc((size_t)N * 4);
    float* ad2     = (float*)alloc((size_t)N * 4);
    float* e2      = (float*)alloc((size_t)E * 4);
    int*   counts  = (int*)alloc((size_t)N * 4);
    int*   cursor  = (int*)alloc((size_t)N * 4);
    int*   row_ofs = (int*)alloc((size_t)(N + 1) * 4);
    int*   perm    = (int*)alloc((size_t)E * 4);

    // ---- choose split-K factor S from remaining workspace ----
    size_t used = (size_t)(w - (char*)d_ws);
    size_t part_bytes = (size_t)N * C * 4;  // 25.2 MB per partial
    int S = 1;
    for (int s = 4; s >= 2; --s) {
        if (used + (size_t)s * part_bytes + (1 << 20) <= ws_size) { S = s; break; }
    }
    float* partials = (S > 1) ? (float*)alloc((size_t)S * part_bytes) : h2;

    // ---- CSR by dst ----
    zero_int_kernel<<<(N + 255) / 256, 256, 0, stream>>>(counts, N);
    zero_int_kernel<<<(N + 255) / 256, 256, 0, stream>>>(cursor, N);
    hist_kernel<<<(E + 255) / 256, 256, 0, stream>>>(dst, counts, E);
    scan_kernel<<<1, NTHREADS, 0, stream>>>(counts, row_ofs, N);
    scatter_kernel<<<(E + 255) / 256, 256, 0, stream>>>(dst, row_ofs, cursor, perm, E);

    // ---- weight transforms (bf16, transposed) ----
    {
        dim3 b(32, 8);
        dim3 g1(HC1 / 32, DIN / 32);
        transpose_bf16_kernel<<<g1, b, 0, stream>>>(W1, W1T, DIN, HC1);
        dim3 g2(C / 32, HC1 / 32);
        transpose_bf16_kernel<<<g2, b, 0, stream>>>(W2, W2T, HC1, C);
    }

    // ---- Layer 1 attention coefficients ----
    wvec_kernel<<<(H1n * DIN * 64 + 255) / 256, 256, 0, stream>>>(W1, a_s1, a_d1, wv, wv + 8 * DIN, DIN, H1n, C);
    alpha16_kernel<<<N / 4, 256, 0, stream>>>((const float4*)x, wv, as1, ad1);
    edge_score_kernel<<<(E * H1n + 255) / 256, 256, 0, stream>>>(src, dst, as1, ad1, e1, E, H1n);
    softmax_kernel<<<(N * H1n + 255) / 256, 256, 0, stream>>>(row_ofs, perm, e1, N, H1n);

    // ---- single-pass 8-head aggregation: x -> zAB (bf16) ----
    aggregate_heads8_kernel<<<N, DIN / 4, 0, stream>>>((const float4*)x, e1, src, row_ofs, perm, zAB, DIN / 4);

    // ---- two head-groups of 4: GEMM1 (bias+ELU, bf16 out) then split-K GEMM2 into partials ----
    const int Kgrp = 4 * C;           // 3072
    const int Kslice = Kgrp / S;      // divisible: 3072 = 2^10*3, S in {1,2,3,4}
    for (int g = 0; g < 2; ++g) {
        {
            dim3 grid(C / 128, N / 128, 4);
            gemm_bf16_kernel<<<grid, 256, 0, stream>>>(
                zAB + (size_t)g * 4 * C, W1T + (size_t)g * 4 * C * DIN,
                HC1, DIN, Kgrp,
                N, C, DIN, /*kofs_per_z=*/0,
                b1 + (size_t)g * 4 * C, o1, nullptr, /*flags=*/1,
                /*bsA=*/C, /*bsBT=*/(long)C * DIN, /*bsC=*/C, /*bsBias=*/C);
        }
        {
            dim3 grid(C / 128, N / 128, S);
            gemm_bf16_kernel<<<grid, 256, 0, stream>>>(
                o1, W2T + (size_t)g * 4 * C,
                Kgrp, HC1, C,
                N, C, Kslice, /*kofs_per_z=*/Kslice,
                nullptr, nullptr, partials, /*flags=*/(g > 0 ? 2 : 0),
                0, 0, /*bsC=*/(long)N * C, 0);
        }
    }
    if (S > 1) {
        int n4 = N * C / 4;
        reduce_partials_kernel<<<(n4 + 255) / 256, 256, 0, stream>>>((const float4*)partials, (float4*)h2, S, n4);
    }

    // ---- Layer 2 (H=1) on h2 ----
    alpha_dot_kernel<<<((size_t)N * 64 + 255) / 256, 256, 0, stream>>>(h2, a_s2, a_d2, as2, ad2, N, 1, C);
    edge_score_kernel<<<(E + 255) / 256, 256, 0, stream>>>(src, dst, as2, ad2, e2, E, 1);
    softmax_kernel<<<(N + 255) / 256, 256, 0, stream>>>(row_ofs, perm, e2, N, 1);
    aggregate_out_kernel<<<N, C / 4, 0, stream>>>((const float4*)h2, e2, src, row_ofs, perm,
                                                  (const float4*)b2, (float4*)d_out, C / 4);
}

// Round 5
// 594.250 us; speedup vs baseline: 5.2833x; 1.0716x over previous
//
#include <hip/hip_runtime.h>
#include <hip/hip_bf16.h>
#include <math.h>

typedef __attribute__((ext_vector_type(4))) float f32x4;
typedef __attribute__((ext_vector_type(8))) short s16x8;

// ---------------- CSR-by-dst construction ----------------

__global__ void zero2_kernel(int* __restrict__ a, int* __restrict__ b, int n) {
    int i = blockIdx.x * blockDim.x + threadIdx.x;
    if (i < n) { a[i] = 0; b[i] = 0; }
}

__global__ void hist_kernel(const int* __restrict__ dst, int* __restrict__ counts, int E) {
    int e = blockIdx.x * blockDim.x + threadIdx.x;
    if (e < E) atomicAdd(&counts[dst[e]], 1);
}

// single block, 1024 threads, parallel Hillis-Steele scan; Nn divisible by 1024
#define SCAN_T 1024
__global__ __launch_bounds__(SCAN_T) void scan_kernel(const int* __restrict__ counts,
                                                      int* __restrict__ row_ofs, int Nn) {
    __shared__ int part[SCAN_T];
    int tid = threadIdx.x;
    int chunk = Nn / SCAN_T;
    int base = tid * chunk;
    int sum = 0;
    for (int i = 0; i < chunk; ++i) sum += counts[base + i];
    part[tid] = sum;
    __syncthreads();
    for (int off = 1; off < SCAN_T; off <<= 1) {
        int v = part[tid];
        int u = (tid >= off) ? part[tid - off] : 0;
        __syncthreads();
        part[tid] = v + u;
        __syncthreads();
    }
    if (tid == SCAN_T - 1) row_ofs[Nn] = part[tid];
    int acc = part[tid] - sum;  // exclusive prefix
    for (int i = 0; i < chunk; ++i) { row_ofs[base + i] = acc; acc += counts[base + i]; }
}

__global__ void scatter_kernel(const int* __restrict__ dst, const int* __restrict__ row_ofs,
                               int* __restrict__ cursor, int* __restrict__ perm, int E) {
    int e = blockIdx.x * blockDim.x + threadIdx.x;
    if (e < E) {
        int d = dst[e];
        int pos = atomicAdd(&cursor[d], 1);
        perm[row_ofs[d] + pos] = e;
    }
}

// ---------------- w_as/w_ad precompute: wv[h*DIN+i] = sum_c W[i, h*C+c] * a[h,c] ----------------
__global__ void wvec_kernel(const float* __restrict__ W, const float* __restrict__ a_s,
                            const float* __restrict__ a_d, float* __restrict__ w_as,
                            float* __restrict__ w_ad, int DIN, int H, int C) {
    int gid = blockIdx.x * blockDim.x + threadIdx.x;
    int wid = gid >> 6;
    int lane = threadIdx.x & 63;
    if (wid >= H * DIN) return;
    int h = wid / DIN, i = wid % DIN;
    const float* wp = W + (size_t)i * H * C + (size_t)h * C;
    const float* sp = a_s + (size_t)h * C;
    const float* dp = a_d + (size_t)h * C;
    float ss = 0.f, sd = 0.f;
    for (int c = lane; c < C; c += 64) {
        float v = wp[c];
        ss += v * sp[c];
        sd += v * dp[c];
    }
    #pragma unroll
    for (int off = 32; off > 0; off >>= 1) {
        ss += __shfl_down(ss, off, 64);
        sd += __shfl_down(sd, off, 64);
    }
    if (lane == 0) { w_as[wid] = ss; w_ad[wid] = sd; }
}

// ---------------- layer-1 alpha dots, all 16 w-vectors LDS-cached; one wave per node ----------------
__global__ __launch_bounds__(256) void alpha16_kernel(const float4* __restrict__ x4,  // [N][192]
                                                      const float* __restrict__ wv,
                                                      float* __restrict__ as_out,    // [N][8]
                                                      float* __restrict__ ad_out) {
    __shared__ float ws[16 * 768];
    int tid = threadIdx.x;
    #pragma unroll
    for (int i = 0; i < 12; ++i)
        ((float4*)ws)[tid + i * 256] = ((const float4*)wv)[tid + i * 256];
    __syncthreads();
    int wvid = tid >> 6, lane = tid & 63;
    int n = blockIdx.x * 4 + wvid;
    float4 xr[3];
    #pragma unroll
    for (int r = 0; r < 3; ++r) xr[r] = x4[(size_t)n * 192 + lane + 64 * r];
    #pragma unroll
    for (int j = 0; j < 16; ++j) {
        const float4* wj = (const float4*)(ws + j * 768);
        float s = 0.f;
        #pragma unroll
        for (int r = 0; r < 3; ++r) {
            float4 wc = wj[lane + 64 * r];
            s += xr[r].x * wc.x + xr[r].y * wc.y + xr[r].z * wc.z + xr[r].w * wc.w;
        }
        #pragma unroll
        for (int off = 32; off > 0; off >>= 1) s += __shfl_down(s, off, 64);
        if (lane == 0) {
            if (j < 8) as_out[n * 8 + j] = s;
            else       ad_out[n * 8 + (j - 8)] = s;
        }
    }
}

// ---------------- layer-2 alpha dots (H=1) ----------------
__global__ void alpha_dot_kernel(const float* __restrict__ feat, const float* __restrict__ w_as,
                                 const float* __restrict__ w_ad, float* __restrict__ as_out,
                                 float* __restrict__ ad_out, int Nn, int H, int D) {
    int gid = blockIdx.x * blockDim.x + threadIdx.x;
    int wid = gid >> 6;
    int lane = threadIdx.x & 63;
    if (wid >= Nn * H) return;
    int n = wid / H, hh = wid % H;
    const float* fp = feat + (size_t)n * D;
    const float* sp = w_as + (size_t)hh * D;
    const float* dp = w_ad + (size_t)hh * D;
    float ss = 0.f, sd = 0.f;
    for (int c = lane; c < D; c += 64) {
        float v = fp[c];
        ss += v * sp[c];
        sd += v * dp[c];
    }
    #pragma unroll
    for (int off = 32; off > 0; off >>= 1) {
        ss += __shfl_down(ss, off, 64);
        sd += __shfl_down(sd, off, 64);
    }
    if (lane == 0) { as_out[wid] = ss; ad_out[wid] = sd; }
}

// ---------------- fused leaky-relu score + segment softmax -> alpha ----------------
__global__ void fused_softmax_kernel(const int* __restrict__ row_ofs, const int* __restrict__ perm,
                                     const int* __restrict__ src,
                                     const float* __restrict__ as, const float* __restrict__ ad,
                                     float* __restrict__ alpha_out, int Nn, int H) {
    int i = blockIdx.x * blockDim.x + threadIdx.x;
    if (i >= Nn * H) return;
    int n = i / H, hh = i % H;
    int s = row_ofs[n], t = row_ofs[n + 1];
    if (s == t) return;
    float adn = ad[n * H + hh];
    float m = -INFINITY;
    for (int j = s; j < t; ++j) {
        float v = as[src[perm[j]] * H + hh] + adn;
        v = v > 0.f ? v : 0.2f * v;
        m = fmaxf(m, v);
    }
    float denom = 0.f;
    for (int j = s; j < t; ++j) {
        float v = as[src[perm[j]] * H + hh] + adn;
        v = v > 0.f ? v : 0.2f * v;
        denom += __expf(v - m);
    }
    float inv = 1.f / (denom + 1e-16f);
    for (int j = s; j < t; ++j) {
        int e = perm[j];
        float v = as[src[e] * H + hh] + adn;
        v = v > 0.f ? v : 0.2f * v;
        alpha_out[(size_t)e * H + hh] = __expf(v - m) * inv;
    }
}

// ---------------- 8-head aggregation of x -> zAB (bf16), single pass ----------------
__device__ inline unsigned short bf16_bits(float f) {
    __hip_bfloat16 b = __float2bfloat16(f);
    return *reinterpret_cast<unsigned short*>(&b);
}

__global__ void aggregate_heads8_kernel(const float4* __restrict__ x4,   // [N][192]
                                        const float* __restrict__ alpha, // [E][8]
                                        const int* __restrict__ src,
                                        const int* __restrict__ row_ofs,
                                        const int* __restrict__ perm,
                                        __hip_bfloat16* __restrict__ zAB, // [N][8*768]
                                        int D4) {
    int n = blockIdx.x;
    int s = row_ofs[n], t = row_ofs[n + 1];
    int j = threadIdx.x;  // 0..191
    float4 acc[8];
    #pragma unroll
    for (int h = 0; h < 8; ++h) acc[h] = make_float4(0.f, 0.f, 0.f, 0.f);
    int e_nxt = (s < t) ? perm[s] : 0;
    int s_nxt = (s < t) ? src[e_nxt] : 0;
    for (int k = s; k < t; ++k) {
        int e = e_nxt, sn = s_nxt;
        if (k + 1 < t) { e_nxt = perm[k + 1]; s_nxt = src[e_nxt]; }
        float4 v = x4[(size_t)sn * D4 + j];
        const float* ap = alpha + (size_t)e * 8;
        #pragma unroll
        for (int h = 0; h < 8; ++h) {
            float a = ap[h];
            acc[h].x += a * v.x; acc[h].y += a * v.y;
            acc[h].z += a * v.z; acc[h].w += a * v.w;
        }
    }
    int D = D4 * 4;
    #pragma unroll
    for (int h = 0; h < 8; ++h) {
        size_t o = (size_t)n * 8 * D + (size_t)h * D + j * 4;
        ushort4 st;
        st.x = bf16_bits(acc[h].x); st.y = bf16_bits(acc[h].y);
        st.z = bf16_bits(acc[h].z); st.w = bf16_bits(acc[h].w);
        *reinterpret_cast<ushort4*>(&zAB[o]) = st;
    }
}

// ---------------- final aggregation (fp32, + bias) ----------------
__global__ void aggregate_out_kernel(const float4* __restrict__ feat4, const float* __restrict__ alpha,
                                     const int* __restrict__ src, const int* __restrict__ row_ofs,
                                     const int* __restrict__ perm, const float4* __restrict__ bias4,
                                     float4* __restrict__ out4, int D4) {
    int n = blockIdx.x;
    int s = row_ofs[n], t = row_ofs[n + 1];
    int j = threadIdx.x;
    float4 acc = make_float4(0.f, 0.f, 0.f, 0.f);
    int e_nxt = (s < t) ? perm[s] : 0;
    int s_nxt = (s < t) ? src[e_nxt] : 0;
    for (int k = s; k < t; ++k) {
        int e = e_nxt, sn = s_nxt;
        if (k + 1 < t) { e_nxt = perm[k + 1]; s_nxt = src[e_nxt]; }
        float a = alpha[e];
        float4 v = feat4[(size_t)sn * D4 + j];
        acc.x += a * v.x; acc.y += a * v.y; acc.z += a * v.z; acc.w += a * v.w;
    }
    float4 b = bias4[j];
    acc.x += b.x; acc.y += b.y; acc.z += b.z; acc.w += b.w;
    out4[(size_t)n * D4 + j] = acc;
}

// ---------------- transpose + fp32->bf16: dst[c][r] = bf16(src[r][c]) ----------------
__global__ void transpose_bf16_kernel(const float* __restrict__ src, __hip_bfloat16* __restrict__ dst,
                                      int R, int Cc) {
    __shared__ float tile[32][33];
    int bx = blockIdx.x * 32;
    int by = blockIdx.y * 32;
    int tx = threadIdx.x, ty = threadIdx.y;  // 32 x 8
    #pragma unroll
    for (int i = 0; i < 32; i += 8)
        tile[ty + i][tx] = src[(size_t)(by + ty + i) * Cc + (bx + tx)];
    __syncthreads();
    #pragma unroll
    for (int i = 0; i < 32; i += 8)
        dst[(size_t)(bx + ty + i) * R + (by + tx)] = __float2bfloat16(tile[tx][ty + i]);
}

// ---------------- partial reduction: h2 = sum_s partials[s] ----------------
__global__ void reduce_partials_kernel(const float4* __restrict__ parts, float4* __restrict__ h2,
                                       int S, int n4) {
    int i = blockIdx.x * blockDim.x + threadIdx.x;
    if (i >= n4) return;
    float4 a = parts[i];
    for (int s = 1; s < S; ++s) {
        float4 b = parts[(size_t)s * n4 + i];
        a.x += b.x; a.y += b.y; a.z += b.z; a.w += b.w;
    }
    h2[i] = a;
}

// ---------------- bf16 MFMA GEMM: C[M,N] = A[M,K] @ BT[N,K]^T ----------------
// 128x128 tile, BK=32, 256 threads (2x2 waves of 64x64), global_load_lds staging.
// Launched with a FLAT grid of GX*GY*GZ blocks; decode uses an XCD-clustering swizzle:
// all GX column-blocks of one (row, z) cluster share blockIdx%8 (same XCD heuristic)
// and are consecutive in dispatch order -> A-tile is fetched from HBM once per XCD.
// Requires (GY*GZ) % 8 == 0.
__device__ inline void gload_lds16(const void* g, void* l) {
    __builtin_amdgcn_global_load_lds((const __attribute__((address_space(1))) unsigned int*)g,
                                     (__attribute__((address_space(3))) unsigned int*)l, 16, 0, 0);
}

__global__ __launch_bounds__(256) void gemm_bf16_kernel(
    const __hip_bfloat16* __restrict__ A,   // [M][lda]
    const __hip_bfloat16* __restrict__ BT,  // [N][ldb]
    int lda, int ldb, int ldc,
    int K, int kofs_per_z,
    const float* __restrict__ bias,
    __hip_bfloat16* __restrict__ Cb,        // bf16 out or null
    float* __restrict__ Cf,                 // fp32 out (used if Cb==null)
    int flags,                              // 1 = elu, 2 = accum (fp32 only)
    long bsA, long bsBT, long bsC, long bsBias,
    int GX, int GY) {
    __shared__ short As[128][32];
    __shared__ short Bs[128][32];

    // XCD-clustering decode
    int lin = blockIdx.x;
    int xcd = lin & 7;
    int u = lin >> 3;
    int bx = u % GX;
    int cg = u / GX;
    int cc = cg * 8 + xcd;
    int by = cc % GY;
    int bz = cc / GY;

    int kofs = bz * kofs_per_z;
    A += (size_t)bz * bsA;
    BT += (size_t)bz * bsBT;
    if (Cb) Cb += (size_t)bz * bsC;
    else    Cf += (size_t)bz * bsC;
    if (bias) bias += (size_t)bz * bsBias;

    int tid = threadIdx.x;
    int lane = tid & 63;
    int wv = tid >> 6;
    int wr = (wv >> 1) * 64;
    int wc = (wv & 1) * 64;
    int ml = lane & 15;
    int q8 = (lane >> 4) * 8;

    int col0 = bx * 128;
    int row0 = by * 128;

    f32x4 acc[4][4];
    #pragma unroll
    for (int i = 0; i < 4; ++i)
        #pragma unroll
        for (int j = 0; j < 4; ++j) acc[i][j] = (f32x4){0.f, 0.f, 0.f, 0.f};

    for (int k0 = 0; k0 < K; k0 += 32) {
        #pragma unroll
        for (int i = 0; i < 2; ++i) {
            int c = tid + i * 256;
            int r = c >> 2;
            int co = (c & 3) << 3;
            gload_lds16(A + (size_t)(row0 + r) * lda + (kofs + k0 + co), ((short*)As) + c * 8);
            gload_lds16(BT + (size_t)(col0 + r) * ldb + (kofs + k0 + co), ((short*)Bs) + c * 8);
        }
        __syncthreads();
        s16x8 af[4], bfr[4];
        #pragma unroll
        for (int t = 0; t < 4; ++t) af[t] = *(const s16x8*)&As[wr + t * 16 + ml][q8];
        #pragma unroll
        for (int t = 0; t < 4; ++t) bfr[t] = *(const s16x8*)&Bs[wc + t * 16 + ml][q8];
        #pragma unroll
        for (int ti = 0; ti < 4; ++ti)
            #pragma unroll
            for (int tj = 0; tj < 4; ++tj)
                acc[ti][tj] = __builtin_amdgcn_mfma_f32_16x16x32_bf16(af[ti], bfr[tj], acc[ti][tj], 0, 0, 0);
        __syncthreads();
    }

    int rbase = row0 + wr + (lane >> 4) * 4;
    int cbase = col0 + wc + ml;
    #pragma unroll
    for (int ti = 0; ti < 4; ++ti) {
        #pragma unroll
        for (int tj = 0; tj < 4; ++tj) {
            int col = cbase + tj * 16;
            float bv = bias ? bias[col] : 0.f;
            #pragma unroll
            for (int r = 0; r < 4; ++r) {
                int row = rbase + ti * 16 + r;
                float v = acc[ti][tj][r] + bv;
                if (flags & 1) v = v > 0.f ? v : expm1f(v);
                size_t idx = (size_t)row * ldc + col;
                if (Cb) Cb[idx] = __float2bfloat16(v);
                else {
                    if (flags & 2) v += Cf[idx];
                    Cf[idx] = v;
                }
            }
        }
    }
}

// ---------------- launch ----------------
extern "C" void kernel_launch(void* const* d_in, const int* in_sizes, int n_in,
                              void* d_out, int out_size, void* d_ws, size_t ws_size,
                              hipStream_t stream) {
    const int N = 8192, E = 65536, DIN = 768, C = 768, H1n = 8;
    const int HC1 = H1n * C;  // 6144

    const float* x    = (const float*)d_in[0];
    const float* W1   = (const float*)d_in[1];
    const float* a_s1 = (const float*)d_in[2];
    const float* a_d1 = (const float*)d_in[3];
    const float* b1   = (const float*)d_in[4];
    const float* W2   = (const float*)d_in[5];
    const float* a_s2 = (const float*)d_in[6];
    const float* a_d2 = (const float*)d_in[7];
    const float* b2   = (const float*)d_in[8];
    const int*   edges = (const int*)d_in[9];
    const int* src = edges;
    const int* dst = edges + E;

    // ---- workspace layout ----
    char* w = (char*)d_ws;
    auto alloc = [&](size_t bytes) -> void* {
        void* p = (void*)w;
        w += (bytes + 255) & ~(size_t)255;
        return p;
    };
    __hip_bfloat16* zAB = (__hip_bfloat16*)alloc((size_t)N * HC1 * 2);      // 100.7 MB
    __hip_bfloat16* o1  = (__hip_bfloat16*)alloc((size_t)N * 4 * C * 2);    // 50.3 MB
    float* h2           = (float*)alloc((size_t)N * C * 4);                 // 25.2 MB
    __hip_bfloat16* W1T = (__hip_bfloat16*)alloc((size_t)HC1 * DIN * 2);    // 9.4 MB
    __hip_bfloat16* W2T = (__hip_bfloat16*)alloc((size_t)C * HC1 * 2);      // 9.4 MB
    float* wv      = (float*)alloc((size_t)16 * DIN * 4);
    float* as1     = (float*)alloc((size_t)N * H1n * 4);
    float* ad1     = (float*)alloc((size_t)N * H1n * 4);
    float* e1      = (float*)alloc((size_t)E * H1n * 4);
    float* as2     = (float*)alloc((size_t)N * 4);
    float* ad2     = (float*)alloc((size_t)N * 4);
    float* e2      = (float*)alloc((size_t)E * 4);
    int*   counts  = (int*)alloc((size_t)N * 4);
    int*   cursor  = (int*)alloc((size_t)N * 4);
    int*   row_ofs = (int*)alloc((size_t)(N + 1) * 4);
    int*   perm    = (int*)alloc((size_t)E * 4);

    // ---- choose split-K factor S: prefer 2 (one full residency round + half the
    // reduce traffic); fall back to 1 if workspace is tight ----
    size_t used = (size_t)(w - (char*)d_ws);
    size_t part_bytes = (size_t)N * C * 4;  // 25.2 MB per partial
    int S = (used + 2 * part_bytes + (1 << 20) <= ws_size) ? 2 : 1;
    float* partials = (S > 1) ? (float*)alloc((size_t)S * part_bytes) : h2;

    // ---- CSR by dst ----
    zero2_kernel<<<(N + 255) / 256, 256, 0, stream>>>(counts, cursor, N);
    hist_kernel<<<(E + 255) / 256, 256, 0, stream>>>(dst, counts, E);
    scan_kernel<<<1, SCAN_T, 0, stream>>>(counts, row_ofs, N);
    scatter_kernel<<<(E + 255) / 256, 256, 0, stream>>>(dst, row_ofs, cursor, perm, E);

    // ---- weight transforms (bf16, transposed) ----
    {
        dim3 b(32, 8);
        dim3 g1(HC1 / 32, DIN / 32);
        transpose_bf16_kernel<<<g1, b, 0, stream>>>(W1, W1T, DIN, HC1);
        dim3 g2(C / 32, HC1 / 32);
        transpose_bf16_kernel<<<g2, b, 0, stream>>>(W2, W2T, HC1, C);
    }

    // ---- Layer 1 attention coefficients ----
    wvec_kernel<<<(H1n * DIN * 64 + 255) / 256, 256, 0, stream>>>(W1, a_s1, a_d1, wv, wv + 8 * DIN, DIN, H1n, C);
    alpha16_kernel<<<N / 4, 256, 0, stream>>>((const float4*)x, wv, as1, ad1);
    fused_softmax_kernel<<<(N * H1n + 255) / 256, 256, 0, stream>>>(row_ofs, perm, src, as1, ad1, e1, N, H1n);

    // ---- single-pass 8-head aggregation: x -> zAB (bf16) ----
    aggregate_heads8_kernel<<<N, DIN / 4, 0, stream>>>((const float4*)x, e1, src, row_ofs, perm, zAB, DIN / 4);

    // ---- two head-groups of 4: GEMM1 (bias+ELU, bf16 out) then split-K GEMM2 ----
    const int Kgrp = 4 * C;           // 3072
    const int Kslice = Kgrp / S;
    for (int g = 0; g < 2; ++g) {
        {
            int GX = C / 128, GY = N / 128, GZ = 4;  // 6 x 64 x 4; GY*GZ=256 % 8 == 0
            gemm_bf16_kernel<<<GX * GY * GZ, 256, 0, stream>>>(
                zAB + (size_t)g * 4 * C, W1T + (size_t)g * 4 * C * DIN,
                HC1, DIN, Kgrp,
                DIN, /*kofs_per_z=*/0,
                b1 + (size_t)g * 4 * C, o1, nullptr, /*flags=*/1,
                /*bsA=*/C, /*bsBT=*/(long)C * DIN, /*bsC=*/C, /*bsBias=*/C,
                GX, GY);
        }
        {
            int GX = C / 128, GY = N / 128, GZ = S;  // GY*GZ = 64*S % 8 == 0
            gemm_bf16_kernel<<<GX * GY * GZ, 256, 0, stream>>>(
                o1, W2T + (size_t)g * 4 * C,
                Kgrp, HC1, C,
                Kslice, /*kofs_per_z=*/Kslice,
                nullptr, nullptr, partials, /*flags=*/(g > 0 ? 2 : 0),
                0, 0, /*bsC=*/(long)N * C, 0,
                GX, GY);
        }
    }
    if (S > 1) {
        int n4 = N * C / 4;
        reduce_partials_kernel<<<(n4 + 255) / 256, 256, 0, stream>>>((const float4*)partials, (float4*)h2, S, n4);
    }

    // ---- Layer 2 (H=1) on h2 ----
    alpha_dot_kernel<<<((size_t)N * 64 + 255) / 256, 256, 0, stream>>>(h2, a_s2, a_d2, as2, ad2, N, 1, C);
    fused_softmax_kernel<<<(N + 255) / 256, 256, 0, stream>>>(row_ofs, perm, src, as2, ad2, e2, N, 1);
    aggregate_out_kernel<<<N, C / 4, 0, stream>>>((const float4*)h2, e2, src, row_ofs, perm,
                                                  (const float4*)b2, (float4*)d_out, C / 4);
}

// Round 6
// 555.380 us; speedup vs baseline: 5.6530x; 1.0700x over previous
//
#include <hip/hip_runtime.h>
#include <hip/hip_bf16.h>
#include <math.h>

typedef __attribute__((ext_vector_type(4))) float f32x4;
typedef __attribute__((ext_vector_type(8))) short s16x8;

// ---------------- CSR-by-dst construction ----------------

__global__ void zero2_kernel(int* __restrict__ a, int* __restrict__ b, int n) {
    int i = blockIdx.x * blockDim.x + threadIdx.x;
    if (i < n) { a[i] = 0; b[i] = 0; }
}

__global__ void hist_kernel(const int* __restrict__ dst, int* __restrict__ counts, int E) {
    int e = blockIdx.x * blockDim.x + threadIdx.x;
    if (e < E) atomicAdd(&counts[dst[e]], 1);
}

// single block, 1024 threads, parallel Hillis-Steele scan; Nn divisible by 1024
#define SCAN_T 1024
__global__ __launch_bounds__(SCAN_T) void scan_kernel(const int* __restrict__ counts,
                                                      int* __restrict__ row_ofs, int Nn) {
    __shared__ int part[SCAN_T];
    int tid = threadIdx.x;
    int chunk = Nn / SCAN_T;
    int base = tid * chunk;
    int sum = 0;
    for (int i = 0; i < chunk; ++i) sum += counts[base + i];
    part[tid] = sum;
    __syncthreads();
    for (int off = 1; off < SCAN_T; off <<= 1) {
        int v = part[tid];
        int u = (tid >= off) ? part[tid - off] : 0;
        __syncthreads();
        part[tid] = v + u;
        __syncthreads();
    }
    if (tid == SCAN_T - 1) row_ofs[Nn] = part[tid];
    int acc = part[tid] - sum;  // exclusive prefix
    for (int i = 0; i < chunk; ++i) { row_ofs[base + i] = acc; acc += counts[base + i]; }
}

__global__ void scatter_kernel(const int* __restrict__ dst, const int* __restrict__ row_ofs,
                               int* __restrict__ cursor, int* __restrict__ perm, int E) {
    int e = blockIdx.x * blockDim.x + threadIdx.x;
    if (e < E) {
        int d = dst[e];
        int pos = atomicAdd(&cursor[d], 1);
        perm[row_ofs[d] + pos] = e;
    }
}

// ---------------- w_as/w_ad precompute: wv[h*DIN+i] = sum_c W[i, h*C+c] * a[h,c] ----------------
__global__ void wvec_kernel(const float* __restrict__ W, const float* __restrict__ a_s,
                            const float* __restrict__ a_d, float* __restrict__ w_as,
                            float* __restrict__ w_ad, int DIN, int H, int C) {
    int gid = blockIdx.x * blockDim.x + threadIdx.x;
    int wid = gid >> 6;
    int lane = threadIdx.x & 63;
    if (wid >= H * DIN) return;
    int h = wid / DIN, i = wid % DIN;
    const float* wp = W + (size_t)i * H * C + (size_t)h * C;
    const float* sp = a_s + (size_t)h * C;
    const float* dp = a_d + (size_t)h * C;
    float ss = 0.f, sd = 0.f;
    for (int c = lane; c < C; c += 64) {
        float v = wp[c];
        ss += v * sp[c];
        sd += v * dp[c];
    }
    #pragma unroll
    for (int off = 32; off > 0; off >>= 1) {
        ss += __shfl_down(ss, off, 64);
        sd += __shfl_down(sd, off, 64);
    }
    if (lane == 0) { w_as[wid] = ss; w_ad[wid] = sd; }
}

// ---------------- layer-1 alpha dots, all 16 w-vectors LDS-cached; one wave per node ----------------
__global__ __launch_bounds__(256) void alpha16_kernel(const float4* __restrict__ x4,  // [N][192]
                                                      const float* __restrict__ wv,
                                                      float* __restrict__ as_out,    // [N][8]
                                                      float* __restrict__ ad_out) {
    __shared__ float ws[16 * 768];
    int tid = threadIdx.x;
    #pragma unroll
    for (int i = 0; i < 12; ++i)
        ((float4*)ws)[tid + i * 256] = ((const float4*)wv)[tid + i * 256];
    __syncthreads();
    int wvid = tid >> 6, lane = tid & 63;
    int n = blockIdx.x * 4 + wvid;
    float4 xr[3];
    #pragma unroll
    for (int r = 0; r < 3; ++r) xr[r] = x4[(size_t)n * 192 + lane + 64 * r];
    #pragma unroll
    for (int j = 0; j < 16; ++j) {
        const float4* wj = (const float4*)(ws + j * 768);
        float s = 0.f;
        #pragma unroll
        for (int r = 0; r < 3; ++r) {
            float4 wc = wj[lane + 64 * r];
            s += xr[r].x * wc.x + xr[r].y * wc.y + xr[r].z * wc.z + xr[r].w * wc.w;
        }
        #pragma unroll
        for (int off = 32; off > 0; off >>= 1) s += __shfl_down(s, off, 64);
        if (lane == 0) {
            if (j < 8) as_out[n * 8 + j] = s;
            else       ad_out[n * 8 + (j - 8)] = s;
        }
    }
}

// ---------------- fused leaky-relu score + segment softmax -> alpha ----------------
__global__ void fused_softmax_kernel(const int* __restrict__ row_ofs, const int* __restrict__ perm,
                                     const int* __restrict__ src,
                                     const float* __restrict__ as, const float* __restrict__ ad,
                                     float* __restrict__ alpha_out, int Nn, int H) {
    int i = blockIdx.x * blockDim.x + threadIdx.x;
    if (i >= Nn * H) return;
    int n = i / H, hh = i % H;
    int s = row_ofs[n], t = row_ofs[n + 1];
    if (s == t) return;
    float adn = ad[n * H + hh];
    float m = -INFINITY;
    for (int j = s; j < t; ++j) {
        float v = as[src[perm[j]] * H + hh] + adn;
        v = v > 0.f ? v : 0.2f * v;
        m = fmaxf(m, v);
    }
    float denom = 0.f;
    for (int j = s; j < t; ++j) {
        float v = as[src[perm[j]] * H + hh] + adn;
        v = v > 0.f ? v : 0.2f * v;
        denom += __expf(v - m);
    }
    float inv = 1.f / (denom + 1e-16f);
    for (int j = s; j < t; ++j) {
        int e = perm[j];
        float v = as[src[e] * H + hh] + adn;
        v = v > 0.f ? v : 0.2f * v;
        alpha_out[(size_t)e * H + hh] = __expf(v - m) * inv;
    }
}

// ---------------- 8-head aggregation of x -> zAB (bf16), single pass, 2-edge unroll ----------------
__device__ inline unsigned short bf16_bits(float f) {
    __hip_bfloat16 b = __float2bfloat16(f);
    return *reinterpret_cast<unsigned short*>(&b);
}

__global__ __launch_bounds__(192) void aggregate_heads8_kernel(
    const float4* __restrict__ x4,   // [N][192]
    const float* __restrict__ alpha, // [E][8]
    const int* __restrict__ src,
    const int* __restrict__ row_ofs,
    const int* __restrict__ perm,
    __hip_bfloat16* __restrict__ zAB, // [N][8*768]
    int D4) {
    int n = blockIdx.x;
    int s = row_ofs[n], t = row_ofs[n + 1];
    int j = threadIdx.x;  // 0..191
    float4 acc[8];
    #pragma unroll
    for (int h = 0; h < 8; ++h) acc[h] = make_float4(0.f, 0.f, 0.f, 0.f);
    int k = s;
    for (; k + 1 < t; k += 2) {
        int e0 = perm[k], e1 = perm[k + 1];
        int s0 = src[e0], s1 = src[e1];
        float4 v0 = x4[(size_t)s0 * D4 + j];
        float4 v1 = x4[(size_t)s1 * D4 + j];
        const float* a0 = alpha + (size_t)e0 * 8;
        const float* a1 = alpha + (size_t)e1 * 8;
        #pragma unroll
        for (int h = 0; h < 8; ++h) {
            float a = a0[h], b = a1[h];
            acc[h].x += a * v0.x + b * v1.x;
            acc[h].y += a * v0.y + b * v1.y;
            acc[h].z += a * v0.z + b * v1.z;
            acc[h].w += a * v0.w + b * v1.w;
        }
    }
    if (k < t) {
        int e0 = perm[k];
        float4 v0 = x4[(size_t)src[e0] * D4 + j];
        const float* a0 = alpha + (size_t)e0 * 8;
        #pragma unroll
        for (int h = 0; h < 8; ++h) {
            float a = a0[h];
            acc[h].x += a * v0.x; acc[h].y += a * v0.y;
            acc[h].z += a * v0.z; acc[h].w += a * v0.w;
        }
    }
    int D = D4 * 4;
    #pragma unroll
    for (int h = 0; h < 8; ++h) {
        size_t o = (size_t)n * 8 * D + (size_t)h * D + j * 4;
        ushort4 st;
        st.x = bf16_bits(acc[h].x); st.y = bf16_bits(acc[h].y);
        st.z = bf16_bits(acc[h].z); st.w = bf16_bits(acc[h].w);
        *reinterpret_cast<ushort4*>(&zAB[o]) = st;
    }
}

// ---------------- final aggregation (fp32, + bias), 2-edge unroll ----------------
__global__ __launch_bounds__(192) void aggregate_out_kernel(
    const float4* __restrict__ feat4, const float* __restrict__ alpha,
    const int* __restrict__ src, const int* __restrict__ row_ofs,
    const int* __restrict__ perm, const float4* __restrict__ bias4,
    float4* __restrict__ out4, int D4) {
    int n = blockIdx.x;
    int s = row_ofs[n], t = row_ofs[n + 1];
    int j = threadIdx.x;
    float4 acc = make_float4(0.f, 0.f, 0.f, 0.f);
    int k = s;
    for (; k + 1 < t; k += 2) {
        int e0 = perm[k], e1 = perm[k + 1];
        float a = alpha[e0], b = alpha[e1];
        float4 v0 = feat4[(size_t)src[e0] * D4 + j];
        float4 v1 = feat4[(size_t)src[e1] * D4 + j];
        acc.x += a * v0.x + b * v1.x; acc.y += a * v0.y + b * v1.y;
        acc.z += a * v0.z + b * v1.z; acc.w += a * v0.w + b * v1.w;
    }
    if (k < t) {
        int e0 = perm[k];
        float a = alpha[e0];
        float4 v0 = feat4[(size_t)src[e0] * D4 + j];
        acc.x += a * v0.x; acc.y += a * v0.y; acc.z += a * v0.z; acc.w += a * v0.w;
    }
    float4 b = bias4[j];
    acc.x += b.x; acc.y += b.y; acc.z += b.z; acc.w += b.w;
    out4[(size_t)n * D4 + j] = acc;
}

// ---------------- transpose + fp32->bf16: dst[c][r] = bf16(src[r][c]) ----------------
__global__ void transpose_bf16_kernel(const float* __restrict__ src, __hip_bfloat16* __restrict__ dst,
                                      int R, int Cc) {
    __shared__ float tile[32][33];
    int bx = blockIdx.x * 32;
    int by = blockIdx.y * 32;
    int tx = threadIdx.x, ty = threadIdx.y;  // 32 x 8
    #pragma unroll
    for (int i = 0; i < 32; i += 8)
        tile[ty + i][tx] = src[(size_t)(by + ty + i) * Cc + (bx + tx)];
    __syncthreads();
    #pragma unroll
    for (int i = 0; i < 32; i += 8)
        dst[(size_t)(bx + ty + i) * R + (by + tx)] = __float2bfloat16(tile[tx][ty + i]);
}

// ---------------- fused: h2 = sum of 4 split-K partials; as2/ad2 = h2 . a_s2 / a_d2 ----------------
// one block per node, 192 threads (3 waves), thread j handles float4 column j
__global__ __launch_bounds__(192) void reduce_dot_kernel(
    const float4* __restrict__ parts,  // [4][N][192]
    const float4* __restrict__ as_w,   // [192] (a_s2)
    const float4* __restrict__ ad_w,   // [192] (a_d2)
    float4* __restrict__ h2,           // [N][192]
    float* __restrict__ as_out, float* __restrict__ ad_out, int NC4) {
    int n = blockIdx.x;
    int j = threadIdx.x;
    size_t idx = (size_t)n * 192 + j;
    float4 a = parts[idx];
    float4 p1 = parts[(size_t)NC4 + idx];
    float4 p2 = parts[2 * (size_t)NC4 + idx];
    float4 p3 = parts[3 * (size_t)NC4 + idx];
    a.x += p1.x + p2.x + p3.x;
    a.y += p1.y + p2.y + p3.y;
    a.z += p1.z + p2.z + p3.z;
    a.w += p1.w + p2.w + p3.w;
    h2[idx] = a;
    float4 ws = as_w[j], wd = ad_w[j];
    float ss = a.x * ws.x + a.y * ws.y + a.z * ws.z + a.w * ws.w;
    float sd = a.x * wd.x + a.y * wd.y + a.z * wd.z + a.w * wd.w;
    #pragma unroll
    for (int off = 32; off > 0; off >>= 1) {
        ss += __shfl_down(ss, off, 64);
        sd += __shfl_down(sd, off, 64);
    }
    __shared__ float red_s[3], red_d[3];
    int wv = j >> 6, lane = j & 63;
    if (lane == 0) { red_s[wv] = ss; red_d[wv] = sd; }
    __syncthreads();
    if (j == 0) {
        as_out[n] = red_s[0] + red_s[1] + red_s[2];
        ad_out[n] = red_d[0] + red_d[1] + red_d[2];
    }
}

// ---------------- bf16 MFMA GEMM: C[M,N] = A[M,K] @ BT[N,K]^T ----------------
// 128x128 tile, BK=32, 256 threads (2x2 waves of 64x64), global_load_lds staging.
// FLAT grid with XCD-clustering swizzle: all GX column-blocks of one (row,z)
// cluster share blockIdx%8 -> same XCD, A-tile fetched from HBM once per XCD.
// Requires (GY*GZ) % 8 == 0.
__device__ inline void gload_lds16(const void* g, void* l) {
    __builtin_amdgcn_global_load_lds((const __attribute__((address_space(1))) unsigned int*)g,
                                     (__attribute__((address_space(3))) unsigned int*)l, 16, 0, 0);
}

__global__ __launch_bounds__(256) void gemm_bf16_kernel(
    const __hip_bfloat16* __restrict__ A,   // [M][lda]
    const __hip_bfloat16* __restrict__ BT,  // [N][ldb]
    int lda, int ldb, int ldc,
    int K, int kofs_per_z,
    const float* __restrict__ bias,
    __hip_bfloat16* __restrict__ Cb,        // bf16 out or null
    float* __restrict__ Cf,                 // fp32 out (used if Cb==null)
    int flags,                              // 1 = elu
    long bsA, long bsBT, long bsC, long bsBias,
    int GX, int GY) {
    __shared__ short As[128][32];
    __shared__ short Bs[128][32];

    // XCD-clustering decode
    int lin = blockIdx.x;
    int xcd = lin & 7;
    int u = lin >> 3;
    int bx = u % GX;
    int cg = u / GX;
    int cc = cg * 8 + xcd;
    int by = cc % GY;
    int bz = cc / GY;

    int kofs = bz * kofs_per_z;
    A += (size_t)bz * bsA;
    BT += (size_t)bz * bsBT;
    if (Cb) Cb += (size_t)bz * bsC;
    else    Cf += (size_t)bz * bsC;
    if (bias) bias += (size_t)bz * bsBias;

    int tid = threadIdx.x;
    int lane = tid & 63;
    int wv = tid >> 6;
    int wr = (wv >> 1) * 64;
    int wc = (wv & 1) * 64;
    int ml = lane & 15;
    int q8 = (lane >> 4) * 8;

    int col0 = bx * 128;
    int row0 = by * 128;

    f32x4 acc[4][4];
    #pragma unroll
    for (int i = 0; i < 4; ++i)
        #pragma unroll
        for (int j = 0; j < 4; ++j) acc[i][j] = (f32x4){0.f, 0.f, 0.f, 0.f};

    for (int k0 = 0; k0 < K; k0 += 32) {
        #pragma unroll
        for (int i = 0; i < 2; ++i) {
            int c = tid + i * 256;
            int r = c >> 2;
            int co = (c & 3) << 3;
            gload_lds16(A + (size_t)(row0 + r) * lda + (kofs + k0 + co), ((short*)As) + c * 8);
            gload_lds16(BT + (size_t)(col0 + r) * ldb + (kofs + k0 + co), ((short*)Bs) + c * 8);
        }
        __syncthreads();
        s16x8 af[4], bfr[4];
        #pragma unroll
        for (int t = 0; t < 4; ++t) af[t] = *(const s16x8*)&As[wr + t * 16 + ml][q8];
        #pragma unroll
        for (int t = 0; t < 4; ++t) bfr[t] = *(const s16x8*)&Bs[wc + t * 16 + ml][q8];
        #pragma unroll
        for (int ti = 0; ti < 4; ++ti)
            #pragma unroll
            for (int tj = 0; tj < 4; ++tj)
                acc[ti][tj] = __builtin_amdgcn_mfma_f32_16x16x32_bf16(af[ti], bfr[tj], acc[ti][tj], 0, 0, 0);
        __syncthreads();
    }

    int rbase = row0 + wr + (lane >> 4) * 4;
    int cbase = col0 + wc + ml;
    #pragma unroll
    for (int ti = 0; ti < 4; ++ti) {
        #pragma unroll
        for (int tj = 0; tj < 4; ++tj) {
            int col = cbase + tj * 16;
            float bv = bias ? bias[col] : 0.f;
            #pragma unroll
            for (int r = 0; r < 4; ++r) {
                int row = rbase + ti * 16 + r;
                float v = acc[ti][tj][r] + bv;
                if (flags & 1) v = v > 0.f ? v : expm1f(v);
                size_t idx = (size_t)row * ldc + col;
                if (Cb) Cb[idx] = __float2bfloat16(v);
                else    Cf[idx] = v;
            }
        }
    }
}

// ---------------- launch ----------------
extern "C" void kernel_launch(void* const* d_in, const int* in_sizes, int n_in,
                              void* d_out, int out_size, void* d_ws, size_t ws_size,
                              hipStream_t stream) {
    const int N = 8192, E = 65536, DIN = 768, C = 768, H1n = 8;
    const int HC1 = H1n * C;  // 6144

    const float* x    = (const float*)d_in[0];
    const float* W1   = (const float*)d_in[1];
    const float* a_s1 = (const float*)d_in[2];
    const float* a_d1 = (const float*)d_in[3];
    const float* b1   = (const float*)d_in[4];
    const float* W2   = (const float*)d_in[5];
    const float* a_s2 = (const float*)d_in[6];
    const float* a_d2 = (const float*)d_in[7];
    const float* b2   = (const float*)d_in[8];
    const int*   edges = (const int*)d_in[9];
    const int* src = edges;
    const int* dst = edges + E;

    // ---- workspace layout (~248.7 MB; round-4 S=2 acceptance proves ws >= 249.8 MB) ----
    char* w = (char*)d_ws;
    auto alloc = [&](size_t bytes) -> void* {
        void* p = (void*)w;
        w += (bytes + 255) & ~(size_t)255;
        return p;
    };
    __hip_bfloat16* zAB = (__hip_bfloat16*)alloc((size_t)N * HC1 * 2);      // 100.7 MB
    __hip_bfloat16* o1  = (__hip_bfloat16*)alloc((size_t)N * HC1 * 2);      // 100.7 MB (all 8 heads)
    float* h2           = (float*)alloc((size_t)N * C * 4);                 // 25.2 MB
    __hip_bfloat16* W1T = (__hip_bfloat16*)alloc((size_t)HC1 * DIN * 2);    // 9.4 MB
    __hip_bfloat16* W2T = (__hip_bfloat16*)alloc((size_t)C * HC1 * 2);      // 9.4 MB
    float* wv      = (float*)alloc((size_t)16 * DIN * 4);
    float* as1     = (float*)alloc((size_t)N * H1n * 4);
    float* ad1     = (float*)alloc((size_t)N * H1n * 4);
    float* e1      = (float*)alloc((size_t)E * H1n * 4);
    float* as2     = (float*)alloc((size_t)N * 4);
    float* ad2     = (float*)alloc((size_t)N * 4);
    float* e2      = (float*)alloc((size_t)E * 4);
    int*   counts  = (int*)alloc((size_t)N * 4);
    int*   cursor  = (int*)alloc((size_t)N * 4);
    int*   row_ofs = (int*)alloc((size_t)(N + 1) * 4);
    int*   perm    = (int*)alloc((size_t)E * 4);

    // split-K partials for GEMM2 (S=4) alias zAB: zAB is dead once GEMM1 has run,
    // and 4 * N*C*4B == N*HC1*2B exactly.
    float* partials = (float*)zAB;
    const int S = 4;

    // ---- CSR by dst ----
    zero2_kernel<<<(N + 255) / 256, 256, 0, stream>>>(counts, cursor, N);
    hist_kernel<<<(E + 255) / 256, 256, 0, stream>>>(dst, counts, E);
    scan_kernel<<<1, SCAN_T, 0, stream>>>(counts, row_ofs, N);
    scatter_kernel<<<(E + 255) / 256, 256, 0, stream>>>(dst, row_ofs, cursor, perm, E);

    // ---- weight transforms (bf16, transposed) ----
    {
        dim3 b(32, 8);
        dim3 g1(HC1 / 32, DIN / 32);
        transpose_bf16_kernel<<<g1, b, 0, stream>>>(W1, W1T, DIN, HC1);
        dim3 g2(C / 32, HC1 / 32);
        transpose_bf16_kernel<<<g2, b, 0, stream>>>(W2, W2T, HC1, C);
    }

    // ---- Layer 1 attention coefficients ----
    wvec_kernel<<<(H1n * DIN * 64 + 255) / 256, 256, 0, stream>>>(W1, a_s1, a_d1, wv, wv + 8 * DIN, DIN, H1n, C);
    alpha16_kernel<<<N / 4, 256, 0, stream>>>((const float4*)x, wv, as1, ad1);
    fused_softmax_kernel<<<(N * H1n + 255) / 256, 256, 0, stream>>>(row_ofs, perm, src, as1, ad1, e1, N, H1n);

    // ---- single-pass 8-head aggregation: x -> zAB (bf16) ----
    aggregate_heads8_kernel<<<N, DIN / 4, 0, stream>>>((const float4*)x, e1, src, row_ofs, perm, zAB, DIN / 4);

    // ---- GEMM1: all 8 heads in one launch; o1 = ELU(z @ W1 + b1) ----
    {
        int GX = C / 128, GY = N / 128, GZ = H1n;  // 6 x 64 x 8 = 3072 blocks
        gemm_bf16_kernel<<<GX * GY * GZ, 256, 0, stream>>>(
            zAB, W1T,
            HC1, DIN, HC1,
            DIN, /*kofs_per_z=*/0,
            b1, o1, nullptr, /*flags=*/1,
            /*bsA=*/C, /*bsBT=*/(long)C * DIN, /*bsC=*/C, /*bsBias=*/C,
            GX, GY);
    }
    // ---- GEMM2: one launch, K=6144 split-K S=4 into partials (aliasing zAB) ----
    {
        int GX = C / 128, GY = N / 128, GZ = S;  // 6 x 64 x 4 = 1536 blocks
        int Kslice = HC1 / S;                    // 1536
        gemm_bf16_kernel<<<GX * GY * GZ, 256, 0, stream>>>(
            o1, W2T,
            HC1, HC1, C,
            Kslice, /*kofs_per_z=*/Kslice,
            nullptr, nullptr, partials, /*flags=*/0,
            0, 0, /*bsC=*/(long)N * C, 0,
            GX, GY);
    }

    // ---- fused: h2 = sum partials ; as2/ad2 = h2 . a_s2 / a_d2 ----
    reduce_dot_kernel<<<N, 192, 0, stream>>>((const float4*)partials, (const float4*)a_s2,
                                             (const float4*)a_d2, (float4*)h2, as2, ad2, N * C / 4);

    // ---- Layer 2 (H=1) softmax + output aggregation ----
    fused_softmax_kernel<<<(N + 255) / 256, 256, 0, stream>>>(row_ofs, perm, src, as2, ad2, e2, N, 1);
    aggregate_out_kernel<<<N, C / 4, 0, stream>>>((const float4*)h2, e2, src, row_ofs, perm,
                                                  (const float4*)b2, (float4*)d_out, C / 4);
}

// Round 7
// 488.584 us; speedup vs baseline: 6.4259x; 1.1367x over previous
//
#include <hip/hip_runtime.h>
#include <hip/hip_bf16.h>
#include <math.h>

typedef __attribute__((ext_vector_type(4))) float f32x4;
typedef __attribute__((ext_vector_type(8))) short s16x8;

#define MAXD 192  // fast-path degree cap for fused softmax (LDS alpha buffer)

// ---------------- CSR-by-dst construction ----------------

__global__ void zero2_kernel(int* __restrict__ a, int* __restrict__ b, int n) {
    int i = blockIdx.x * blockDim.x + threadIdx.x;
    if (i < n) { a[i] = 0; b[i] = 0; }
}

__global__ void hist_kernel(const int* __restrict__ dst, int* __restrict__ counts, int E) {
    int e = blockIdx.x * blockDim.x + threadIdx.x;
    if (e < E) atomicAdd(&counts[dst[e]], 1);
}

#define SCAN_T 1024
__global__ __launch_bounds__(SCAN_T) void scan_kernel(const int* __restrict__ counts,
                                                      int* __restrict__ row_ofs, int Nn) {
    __shared__ int part[SCAN_T];
    int tid = threadIdx.x;
    int chunk = Nn / SCAN_T;
    int base = tid * chunk;
    int sum = 0;
    for (int i = 0; i < chunk; ++i) sum += counts[base + i];
    part[tid] = sum;
    __syncthreads();
    for (int off = 1; off < SCAN_T; off <<= 1) {
        int v = part[tid];
        int u = (tid >= off) ? part[tid - off] : 0;
        __syncthreads();
        part[tid] = v + u;
        __syncthreads();
    }
    if (tid == SCAN_T - 1) row_ofs[Nn] = part[tid];
    int acc = part[tid] - sum;  // exclusive prefix
    for (int i = 0; i < chunk; ++i) { row_ofs[base + i] = acc; acc += counts[base + i]; }
}

__global__ void scatter_kernel(const int* __restrict__ dst, const int* __restrict__ row_ofs,
                               int* __restrict__ cursor, int* __restrict__ perm, int E) {
    int e = blockIdx.x * blockDim.x + threadIdx.x;
    if (e < E) {
        int d = dst[e];
        int pos = atomicAdd(&cursor[d], 1);
        perm[row_ofs[d] + pos] = e;
    }
}

// ---------------- w_as/w_ad precompute ----------------
__global__ void wvec_kernel(const float* __restrict__ W, const float* __restrict__ a_s,
                            const float* __restrict__ a_d, float* __restrict__ w_as,
                            float* __restrict__ w_ad, int DIN, int H, int C) {
    int gid = blockIdx.x * blockDim.x + threadIdx.x;
    int wid = gid >> 6;
    int lane = threadIdx.x & 63;
    if (wid >= H * DIN) return;
    int h = wid / DIN, i = wid % DIN;
    const float* wp = W + (size_t)i * H * C + (size_t)h * C;
    const float* sp = a_s + (size_t)h * C;
    const float* dp = a_d + (size_t)h * C;
    float ss = 0.f, sd = 0.f;
    for (int c = lane; c < C; c += 64) {
        float v = wp[c];
        ss += v * sp[c];
        sd += v * dp[c];
    }
    #pragma unroll
    for (int off = 32; off > 0; off >>= 1) {
        ss += __shfl_down(ss, off, 64);
        sd += __shfl_down(sd, off, 64);
    }
    if (lane == 0) { w_as[wid] = ss; w_ad[wid] = sd; }
}

// ---------------- layer-1 alpha dots, w-vectors LDS-cached; one wave per node ----------------
__global__ __launch_bounds__(256) void alpha16_kernel(const float4* __restrict__ x4,
                                                      const float* __restrict__ wv,
                                                      float* __restrict__ as_out,
                                                      float* __restrict__ ad_out) {
    __shared__ float ws[16 * 768];
    int tid = threadIdx.x;
    #pragma unroll
    for (int i = 0; i < 12; ++i)
        ((float4*)ws)[tid + i * 256] = ((const float4*)wv)[tid + i * 256];
    __syncthreads();
    int wvid = tid >> 6, lane = tid & 63;
    int n = blockIdx.x * 4 + wvid;
    float4 xr[3];
    #pragma unroll
    for (int r = 0; r < 3; ++r) xr[r] = x4[(size_t)n * 192 + lane + 64 * r];
    #pragma unroll
    for (int j = 0; j < 16; ++j) {
        const float4* wj = (const float4*)(ws + j * 768);
        float s = 0.f;
        #pragma unroll
        for (int r = 0; r < 3; ++r) {
            float4 wc = wj[lane + 64 * r];
            s += xr[r].x * wc.x + xr[r].y * wc.y + xr[r].z * wc.z + xr[r].w * wc.w;
        }
        #pragma unroll
        for (int off = 32; off > 0; off >>= 1) s += __shfl_down(s, off, 64);
        if (lane == 0) {
            if (j < 8) as_out[n * 8 + j] = s;
            else       ad_out[n * 8 + (j - 8)] = s;
        }
    }
}

// ---------------- FUSED: per-node softmax (8 heads) + 8-head aggregation -> zAB bf16 ----------------
__device__ inline unsigned short bf16_bits(float f) {
    __hip_bfloat16 b = __float2bfloat16(f);
    return *reinterpret_cast<unsigned short*>(&b);
}

__global__ __launch_bounds__(192) void agg8_fused_kernel(
    const float4* __restrict__ x4,    // [N][192]
    const float* __restrict__ as1,    // [N][8]
    const float* __restrict__ ad1,    // [N][8]
    const int* __restrict__ src,
    const int* __restrict__ row_ofs,
    const int* __restrict__ perm,
    float* __restrict__ e1g,          // [E][8] global fallback alpha
    __hip_bfloat16* __restrict__ zAB, // [N][8*768]
    int D4) {
    __shared__ float alds[MAXD * 8];
    __shared__ float mh[8], dh[8];
    int n = blockIdx.x;
    int s = row_ofs[n], t = row_ofs[n + 1];
    int d = t - s;
    int tid = threadIdx.x;
    bool big = d > MAXD;
    if (!big) {
        int eh = tid & 7, ei = tid >> 3;  // ei in 0..23
        float adn = ad1[n * 8 + eh];
        for (int base = 0; base < d; base += 24) {
            int j = base + ei;
            if (j < d) {
                int e = perm[s + j];
                float v = as1[src[e] * 8 + eh] + adn;
                v = v > 0.f ? v : 0.2f * v;
                alds[j * 8 + eh] = v;
            }
        }
        __syncthreads();
        if (tid < 8) {
            float m = -INFINITY;
            for (int j = 0; j < d; ++j) m = fmaxf(m, alds[j * 8 + tid]);
            float den = 0.f;
            for (int j = 0; j < d; ++j) den += __expf(alds[j * 8 + tid] - m);
            mh[tid] = m; dh[tid] = 1.f / (den + 1e-16f);
        }
        __syncthreads();
        for (int base = 0; base < d; base += 24) {
            int j = base + ei;
            if (j < d) alds[j * 8 + eh] = __expf(alds[j * 8 + eh] - mh[eh]) * dh[eh];
        }
        __syncthreads();
    } else {
        if (tid < 8) {
            int hh = tid;
            float adn = ad1[n * 8 + hh];
            float m = -INFINITY;
            for (int j = s; j < t; ++j) {
                float v = as1[src[perm[j]] * 8 + hh] + adn;
                v = v > 0.f ? v : 0.2f * v;
                m = fmaxf(m, v);
            }
            float den = 0.f;
            for (int j = s; j < t; ++j) {
                float v = as1[src[perm[j]] * 8 + hh] + adn;
                v = v > 0.f ? v : 0.2f * v;
                den += __expf(v - m);
            }
            float inv = 1.f / (den + 1e-16f);
            for (int j = s; j < t; ++j) {
                int e = perm[j];
                float v = as1[src[e] * 8 + hh] + adn;
                v = v > 0.f ? v : 0.2f * v;
                e1g[(size_t)e * 8 + hh] = __expf(v - m) * inv;
            }
        }
        __syncthreads();
    }

    // aggregation: thread j handles float4 column j for all 8 heads
    int j = tid;
    float4 acc[8];
    #pragma unroll
    for (int h = 0; h < 8; ++h) acc[h] = make_float4(0.f, 0.f, 0.f, 0.f);
    int k = s;
    for (; k + 1 < t; k += 2) {
        int e0 = perm[k], e1 = perm[k + 1];
        float4 v0 = x4[(size_t)src[e0] * D4 + j];
        float4 v1 = x4[(size_t)src[e1] * D4 + j];
        const float* a0 = big ? &e1g[(size_t)e0 * 8] : &alds[(k - s) * 8];
        const float* a1 = big ? &e1g[(size_t)e1 * 8] : &alds[(k + 1 - s) * 8];
        #pragma unroll
        for (int h = 0; h < 8; ++h) {
            float a = a0[h], b = a1[h];
            acc[h].x += a * v0.x + b * v1.x;
            acc[h].y += a * v0.y + b * v1.y;
            acc[h].z += a * v0.z + b * v1.z;
            acc[h].w += a * v0.w + b * v1.w;
        }
    }
    if (k < t) {
        int e0 = perm[k];
        float4 v0 = x4[(size_t)src[e0] * D4 + j];
        const float* a0 = big ? &e1g[(size_t)e0 * 8] : &alds[(k - s) * 8];
        #pragma unroll
        for (int h = 0; h < 8; ++h) {
            float a = a0[h];
            acc[h].x += a * v0.x; acc[h].y += a * v0.y;
            acc[h].z += a * v0.z; acc[h].w += a * v0.w;
        }
    }
    int D = D4 * 4;
    #pragma unroll
    for (int h = 0; h < 8; ++h) {
        size_t o = (size_t)n * 8 * D + (size_t)h * D + j * 4;
        ushort4 st;
        st.x = bf16_bits(acc[h].x); st.y = bf16_bits(acc[h].y);
        st.z = bf16_bits(acc[h].z); st.w = bf16_bits(acc[h].w);
        *reinterpret_cast<ushort4*>(&zAB[o]) = st;
    }
}

// ---------------- FUSED: layer-2 softmax (H=1) + output aggregation (+bias) ----------------
__global__ __launch_bounds__(192) void out_fused_kernel(
    const float4* __restrict__ feat4,  // h2 [N][192]
    const float* __restrict__ as2,     // [N]
    const float* __restrict__ ad2,     // [N]
    const int* __restrict__ src,
    const int* __restrict__ row_ofs,
    const int* __restrict__ perm,
    float* __restrict__ e2g,           // [E] global fallback alpha
    const float4* __restrict__ bias4,
    float4* __restrict__ out4, int D4) {
    __shared__ float alds[MAXD];
    __shared__ float minv[2];
    int n = blockIdx.x;
    int s = row_ofs[n], t = row_ofs[n + 1];
    int d = t - s;
    int tid = threadIdx.x;
    bool big = d > MAXD;
    if (!big) {
        float adn = ad2[n];
        if (tid < d) {
            float v = as2[src[perm[s + tid]]] + adn;
            v = v > 0.f ? v : 0.2f * v;
            alds[tid] = v;
        }
        __syncthreads();
        if (tid == 0) {
            float m = -INFINITY;
            for (int j = 0; j < d; ++j) m = fmaxf(m, alds[j]);
            float den = 0.f;
            for (int j = 0; j < d; ++j) den += __expf(alds[j] - m);
            minv[0] = m; minv[1] = 1.f / (den + 1e-16f);
        }
        __syncthreads();
        if (tid < d) alds[tid] = __expf(alds[tid] - minv[0]) * minv[1];
        __syncthreads();
    } else {
        if (tid == 0) {
            float adn = ad2[n];
            float m = -INFINITY;
            for (int j = s; j < t; ++j) {
                float v = as2[src[perm[j]]] + adn;
                v = v > 0.f ? v : 0.2f * v;
                m = fmaxf(m, v);
            }
            float den = 0.f;
            for (int j = s; j < t; ++j) {
                float v = as2[src[perm[j]]] + adn;
                v = v > 0.f ? v : 0.2f * v;
                den += __expf(v - m);
            }
            float inv = 1.f / (den + 1e-16f);
            for (int j = s; j < t; ++j) {
                int e = perm[j];
                float v = as2[src[e]] + adn;
                v = v > 0.f ? v : 0.2f * v;
                e2g[e] = __expf(v - m) * inv;
            }
        }
        __syncthreads();
    }

    int j = tid;
    float4 acc = make_float4(0.f, 0.f, 0.f, 0.f);
    int k = s;
    for (; k + 1 < t; k += 2) {
        int e0 = perm[k], e1 = perm[k + 1];
        float a = big ? e2g[e0] : alds[k - s];
        float b = big ? e2g[e1] : alds[k + 1 - s];
        float4 v0 = feat4[(size_t)src[e0] * D4 + j];
        float4 v1 = feat4[(size_t)src[e1] * D4 + j];
        acc.x += a * v0.x + b * v1.x; acc.y += a * v0.y + b * v1.y;
        acc.z += a * v0.z + b * v1.z; acc.w += a * v0.w + b * v1.w;
    }
    if (k < t) {
        int e0 = perm[k];
        float a = big ? e2g[e0] : alds[k - s];
        float4 v0 = feat4[(size_t)src[e0] * D4 + j];
        acc.x += a * v0.x; acc.y += a * v0.y; acc.z += a * v0.z; acc.w += a * v0.w;
    }
    float4 b = bias4[j];
    acc.x += b.x; acc.y += b.y; acc.z += b.z; acc.w += b.w;
    out4[(size_t)n * D4 + j] = acc;
}

// ---------------- transpose + fp32->bf16 ----------------
__global__ void transpose_bf16_kernel(const float* __restrict__ src, __hip_bfloat16* __restrict__ dst,
                                      int R, int Cc) {
    __shared__ float tile[32][33];
    int bx = blockIdx.x * 32;
    int by = blockIdx.y * 32;
    int tx = threadIdx.x, ty = threadIdx.y;  // 32 x 8
    #pragma unroll
    for (int i = 0; i < 32; i += 8)
        tile[ty + i][tx] = src[(size_t)(by + ty + i) * Cc + (bx + tx)];
    __syncthreads();
    #pragma unroll
    for (int i = 0; i < 32; i += 8)
        dst[(size_t)(bx + ty + i) * R + (by + tx)] = __float2bfloat16(tile[tx][ty + i]);
}

// ---------------- fused: h2 = p0+p1 (split-K S=2); as2/ad2 = h2 . a_s2 / a_d2 ----------------
__global__ __launch_bounds__(192) void reduce_dot_kernel(
    const float4* __restrict__ parts,  // [2][N][192]
    const float4* __restrict__ as_w, const float4* __restrict__ ad_w,
    float4* __restrict__ h2,
    float* __restrict__ as_out, float* __restrict__ ad_out, int NC4) {
    int n = blockIdx.x;
    int j = threadIdx.x;
    size_t idx = (size_t)n * 192 + j;
    float4 a = parts[idx];
    float4 p1 = parts[(size_t)NC4 + idx];
    a.x += p1.x; a.y += p1.y; a.z += p1.z; a.w += p1.w;
    h2[idx] = a;
    float4 ws = as_w[j], wd = ad_w[j];
    float ss = a.x * ws.x + a.y * ws.y + a.z * ws.z + a.w * ws.w;
    float sd = a.x * wd.x + a.y * wd.y + a.z * wd.z + a.w * wd.w;
    #pragma unroll
    for (int off = 32; off > 0; off >>= 1) {
        ss += __shfl_down(ss, off, 64);
        sd += __shfl_down(sd, off, 64);
    }
    __shared__ float red_s[3], red_d[3];
    int wv = j >> 6, lane = j & 63;
    if (lane == 0) { red_s[wv] = ss; red_d[wv] = sd; }
    __syncthreads();
    if (j == 0) {
        as_out[n] = red_s[0] + red_s[1] + red_s[2];
        ad_out[n] = red_d[0] + red_d[1] + red_d[2];
    }
}

// ---------------- bf16 MFMA GEMM: C[M,N] = A[M,K] @ BT[N,K]^T ----------------
// 128x128 tile, BK=32, 256 threads (2x2 waves of 64x64), global_load_lds staging,
// XCD-clustering swizzle (requires (GY*GZ)%8==0), hoisted staging pointers.
__device__ inline void gload_lds16(const void* g, void* l) {
    __builtin_amdgcn_global_load_lds((const __attribute__((address_space(1))) unsigned int*)g,
                                     (__attribute__((address_space(3))) unsigned int*)l, 16, 0, 0);
}

__global__ __launch_bounds__(256) void gemm_bf16_kernel(
    const __hip_bfloat16* __restrict__ A,   // [M][lda]
    const __hip_bfloat16* __restrict__ BT,  // [N][ldb]
    int lda, int ldb, int ldc,
    int K, int kofs_per_z,
    const float* __restrict__ bias,
    __hip_bfloat16* __restrict__ Cb,        // bf16 out or null
    float* __restrict__ Cf,                 // fp32 out (used if Cb==null)
    int flags,                              // 1 = elu
    long bsA, long bsBT, long bsC, long bsBias,
    int GX, int GY) {
    __shared__ short As[128][32];
    __shared__ short Bs[128][32];

    int lin = blockIdx.x;
    int xcd = lin & 7;
    int u = lin >> 3;
    int bx = u % GX;
    int cg = u / GX;
    int cc = cg * 8 + xcd;
    int by = cc % GY;
    int bz = cc / GY;

    int kofs = bz * kofs_per_z;
    A += (size_t)bz * bsA;
    BT += (size_t)bz * bsBT;
    if (Cb) Cb += (size_t)bz * bsC;
    else    Cf += (size_t)bz * bsC;
    if (bias) bias += (size_t)bz * bsBias;

    int tid = threadIdx.x;
    int lane = tid & 63;
    int wv = tid >> 6;
    int wr = (wv >> 1) * 64;
    int wc = (wv & 1) * 64;
    int ml = lane & 15;
    int q8 = (lane >> 4) * 8;

    int col0 = bx * 128;
    int row0 = by * 128;

    // hoisted staging pointers: thread stages rows (tid>>2) and (tid>>2)+64,
    // k-offset (tid&3)*8; advance 32 elements per iteration
    const __hip_bfloat16* gA = A + (size_t)(row0 + (tid >> 2)) * lda + kofs + ((tid & 3) << 3);
    const __hip_bfloat16* gB = BT + (size_t)(col0 + (tid >> 2)) * ldb + kofs + ((tid & 3) << 3);
    size_t strA = (size_t)64 * lda, strB = (size_t)64 * ldb;
    short* lA0 = ((short*)As) + tid * 8;
    short* lA1 = ((short*)As) + (tid + 256) * 8;
    short* lB0 = ((short*)Bs) + tid * 8;
    short* lB1 = ((short*)Bs) + (tid + 256) * 8;

    // hoisted fragment pointers (constant LDS addresses)
    const s16x8* pA[4];
    const s16x8* pB[4];
    #pragma unroll
    for (int t = 0; t < 4; ++t) {
        pA[t] = (const s16x8*)&As[wr + t * 16 + ml][q8];
        pB[t] = (const s16x8*)&Bs[wc + t * 16 + ml][q8];
    }

    f32x4 acc[4][4];
    #pragma unroll
    for (int i = 0; i < 4; ++i)
        #pragma unroll
        for (int j = 0; j < 4; ++j) acc[i][j] = (f32x4){0.f, 0.f, 0.f, 0.f};

    for (int k0 = 0; k0 < K; k0 += 32) {
        gload_lds16(gA, lA0);
        gload_lds16(gA + strA, lA1);
        gload_lds16(gB, lB0);
        gload_lds16(gB + strB, lB1);
        gA += 32; gB += 32;
        __syncthreads();
        s16x8 af[4], bfr[4];
        #pragma unroll
        for (int t = 0; t < 4; ++t) af[t] = *pA[t];
        #pragma unroll
        for (int t = 0; t < 4; ++t) bfr[t] = *pB[t];
        #pragma unroll
        for (int ti = 0; ti < 4; ++ti)
            #pragma unroll
            for (int tj = 0; tj < 4; ++tj)
                acc[ti][tj] = __builtin_amdgcn_mfma_f32_16x16x32_bf16(af[ti], bfr[tj], acc[ti][tj], 0, 0, 0);
        __syncthreads();
    }

    int rbase = row0 + wr + (lane >> 4) * 4;
    int cbase = col0 + wc + ml;
    #pragma unroll
    for (int ti = 0; ti < 4; ++ti) {
        #pragma unroll
        for (int tj = 0; tj < 4; ++tj) {
            int col = cbase + tj * 16;
            float bv = bias ? bias[col] : 0.f;
            #pragma unroll
            for (int r = 0; r < 4; ++r) {
                int row = rbase + ti * 16 + r;
                float v = acc[ti][tj][r] + bv;
                if (flags & 1) {
                    float ev = __expf(v) - 1.f;  // elu via fast exp (select, no branch)
                    v = v > 0.f ? v : ev;
                }
                size_t idx = (size_t)row * ldc + col;
                if (Cb) Cb[idx] = __float2bfloat16(v);
                else    Cf[idx] = v;
            }
        }
    }
}

// ---------------- launch ----------------
extern "C" void kernel_launch(void* const* d_in, const int* in_sizes, int n_in,
                              void* d_out, int out_size, void* d_ws, size_t ws_size,
                              hipStream_t stream) {
    const int N = 8192, E = 65536, DIN = 768, C = 768, H1n = 8;
    const int HC1 = H1n * C;  // 6144

    const float* x    = (const float*)d_in[0];
    const float* W1   = (const float*)d_in[1];
    const float* a_s1 = (const float*)d_in[2];
    const float* a_d1 = (const float*)d_in[3];
    const float* b1   = (const float*)d_in[4];
    const float* W2   = (const float*)d_in[5];
    const float* a_s2 = (const float*)d_in[6];
    const float* a_d2 = (const float*)d_in[7];
    const float* b2   = (const float*)d_in[8];
    const int*   edges = (const int*)d_in[9];
    const int* src = edges;
    const int* dst = edges + E;

    // ---- workspace layout (~248.7 MB) ----
    char* w = (char*)d_ws;
    auto alloc = [&](size_t bytes) -> void* {
        void* p = (void*)w;
        w += (bytes + 255) & ~(size_t)255;
        return p;
    };
    __hip_bfloat16* zAB = (__hip_bfloat16*)alloc((size_t)N * HC1 * 2);      // 100.7 MB
    __hip_bfloat16* o1  = (__hip_bfloat16*)alloc((size_t)N * HC1 * 2);      // 100.7 MB
    float* h2           = (float*)alloc((size_t)N * C * 4);                 // 25.2 MB
    __hip_bfloat16* W1T = (__hip_bfloat16*)alloc((size_t)HC1 * DIN * 2);    // 9.4 MB
    __hip_bfloat16* W2T = (__hip_bfloat16*)alloc((size_t)C * HC1 * 2);      // 9.4 MB
    float* wv      = (float*)alloc((size_t)16 * DIN * 4);
    float* as1     = (float*)alloc((size_t)N * H1n * 4);
    float* ad1     = (float*)alloc((size_t)N * H1n * 4);
    float* e1      = (float*)alloc((size_t)E * H1n * 4);   // fallback alpha (deg > MAXD)
    float* as2     = (float*)alloc((size_t)N * 4);
    float* ad2     = (float*)alloc((size_t)N * 4);
    float* e2      = (float*)alloc((size_t)E * 4);         // fallback alpha (deg > MAXD)
    int*   counts  = (int*)alloc((size_t)N * 4);
    int*   cursor  = (int*)alloc((size_t)N * 4);
    int*   row_ofs = (int*)alloc((size_t)(N + 1) * 4);
    int*   perm    = (int*)alloc((size_t)E * 4);

    // split-K partials for GEMM2 (S=2) alias zAB (dead after GEMM1; 2*25.2 <= 100.7 MB)
    float* partials = (float*)zAB;
    const int S = 2;

    // ---- CSR by dst ----
    zero2_kernel<<<(N + 255) / 256, 256, 0, stream>>>(counts, cursor, N);
    hist_kernel<<<(E + 255) / 256, 256, 0, stream>>>(dst, counts, E);
    scan_kernel<<<1, SCAN_T, 0, stream>>>(counts, row_ofs, N);
    scatter_kernel<<<(E + 255) / 256, 256, 0, stream>>>(dst, row_ofs, cursor, perm, E);

    // ---- weight transforms (bf16, transposed) ----
    {
        dim3 b(32, 8);
        dim3 g1(HC1 / 32, DIN / 32);
        transpose_bf16_kernel<<<g1, b, 0, stream>>>(W1, W1T, DIN, HC1);
        dim3 g2(C / 32, HC1 / 32);
        transpose_bf16_kernel<<<g2, b, 0, stream>>>(W2, W2T, HC1, C);
    }

    // ---- Layer 1 attention coefficients ----
    wvec_kernel<<<(H1n * DIN * 64 + 255) / 256, 256, 0, stream>>>(W1, a_s1, a_d1, wv, wv + 8 * DIN, DIN, H1n, C);
    alpha16_kernel<<<N / 4, 256, 0, stream>>>((const float4*)x, wv, as1, ad1);

    // ---- fused softmax + 8-head aggregation: x -> zAB (bf16) ----
    agg8_fused_kernel<<<N, 192, 0, stream>>>((const float4*)x, as1, ad1, src, row_ofs, perm,
                                             e1, zAB, DIN / 4);

    // ---- GEMM1: all 8 heads; o1 = ELU(z @ W1 + b1) ----
    {
        int GX = C / 128, GY = N / 128, GZ = H1n;  // 6 x 64 x 8 = 3072 blocks
        gemm_bf16_kernel<<<GX * GY * GZ, 256, 0, stream>>>(
            zAB, W1T,
            HC1, DIN, HC1,
            DIN, /*kofs_per_z=*/0,
            b1, o1, nullptr, /*flags=*/1,
            /*bsA=*/C, /*bsBT=*/(long)C * DIN, /*bsC=*/C, /*bsBias=*/C,
            GX, GY);
    }
    // ---- GEMM2: K=6144 split-K S=2 into partials (aliasing zAB) ----
    {
        int GX = C / 128, GY = N / 128, GZ = S;  // 6 x 64 x 2 = 768 blocks
        int Kslice = HC1 / S;                    // 3072 -> 96 iters/block
        gemm_bf16_kernel<<<GX * GY * GZ, 256, 0, stream>>>(
            o1, W2T,
            HC1, HC1, C,
            Kslice, /*kofs_per_z=*/Kslice,
            nullptr, nullptr, partials, /*flags=*/0,
            0, 0, /*bsC=*/(long)N * C, 0,
            GX, GY);
    }

    // ---- fused: h2 = p0 + p1 ; as2/ad2 = h2 . a_s2 / a_d2 ----
    reduce_dot_kernel<<<N, 192, 0, stream>>>((const float4*)partials, (const float4*)a_s2,
                                             (const float4*)a_d2, (float4*)h2, as2, ad2, N * C / 4);

    // ---- fused layer-2 softmax + output aggregation ----
    out_fused_kernel<<<N, 192, 0, stream>>>((const float4*)h2, as2, ad2, src, row_ofs, perm,
                                            e2, (const float4*)b2, (float4*)d_out, C / 4);
}